// Round 9
// baseline (73.919 us; speedup 1.0000x reference)
//
#include <hip/hip_runtime.h>
#include <math.h>

#define B_    16
#define T_    2048
#define DIM_  512
#define M_    (B_*T_)

typedef __attribute__((ext_vector_type(8))) short short8_t;   // 8 x bf16 bits
typedef __attribute__((ext_vector_type(4))) float f32x4;

__device__ __forceinline__ float clamp01(float x){ return fminf(fmaxf(x,0.f),1.f); }
__device__ __forceinline__ float clampf(float x,float lo,float hi){ return fminf(fmaxf(x,lo),hi); }
__device__ __forceinline__ float gelu_exact(float x){ return 0.5f*x*(1.f+erff(x*0.70710678118654752f)); }
__device__ __forceinline__ unsigned short bf16_rne(float f){
  unsigned u = __float_as_uint(f);
  unsigned r = (u + 0x7fffu + ((u>>16)&1u)) >> 16;
  return (unsigned short)r;
}
__device__ __forceinline__ float fast_tanh(float x){
  float e = __expf(2.0f*x);
  return 1.0f - 2.0f*__builtin_amdgcn_rcpf(e + 1.0f);
}
// tanh-form GELU (max abs dev ~3e-4; epilogue only)
__device__ __forceinline__ float gelu_fast(float x){
  float u = 0.7978845608028654f*fmaf(0.044715f*x, x*x, x);
  return 0.5f*x*(1.f + fast_tanh(u));
}
__device__ __forceinline__ unsigned cvt_pk_bf16(float lo, float hi){
  unsigned r;
  asm("v_cvt_pk_bf16_f32 %0, %1, %2" : "=v"(r) : "v"(lo), "v"(hi));
  return r;
}
__device__ __forceinline__ int idx32(int t){ return t + (t>>5); }  // pad stride 33

// ---------------------------------------------------------------------------
// P1: 160 blocks x 512 threads.
//  blk   0..127 : spk_ctx[b, s*64 .. s*64+64)  (b=blk>>3, s=blk&7)
//  blk 128..143 : EMA scan + excl cumsum       (b=blk-128)
//  blk 144..159 : rW1[0:512] -> bf16 Bt[kt][col][32]  (kt=blk-144, linear)
// ---------------------------------------------------------------------------
__global__ __launch_bounds__(512) void k_p1(
    const float* __restrict__ log_anchor, const float* __restrict__ unit_mask,
    const float* __restrict__ sealed_mask, const float* __restrict__ silence_mask,
    const float* __restrict__ local_rate_ema,
    const float* __restrict__ spk_embed, const float* __restrict__ spk_W,
    const float* __restrict__ spk_b, const float* __restrict__ rW1,
    float* __restrict__ lr_seq, float* __restrict__ prefix_prev,
    float* __restrict__ spk_ctx, unsigned short* __restrict__ BtG)
{
  __shared__ float shbuf[12672];
  const int tid = threadIdx.x;
  const int blk = blockIdx.x;

  if (blk < 128){
    const int b = blk >> 3, n0 = (blk & 7)*64;
    float* se      = shbuf;
    float* partial = shbuf + 512;
    se[tid] = spk_embed[b*512 + tid];
    __syncthreads();
    const int nq = tid & 15, q = tid >> 4;
    float a0=0.f, a1=0.f, a2=0.f, a3=0.f;
    const float* wp = spk_W + (q*16)*512 + n0 + nq*4;
    #pragma unroll
    for (int kk = 0; kk < 16; ++kk){
      float s = se[q*16 + kk];
      float4 v = *(const float4*)(wp + kk*512);
      a0 = fmaf(s, v.x, a0); a1 = fmaf(s, v.y, a1);
      a2 = fmaf(s, v.z, a2); a3 = fmaf(s, v.w, a3);
    }
    *(float4*)&partial[q*64 + nq*4] = make_float4(a0,a1,a2,a3);
    __syncthreads();
    if (tid < 64){
      float acc = spk_b[n0 + tid];
      #pragma unroll
      for (int qq = 0; qq < 32; ++qq) acc += partial[qq*64 + tid];
      spk_ctx[b*512 + n0 + tid] = tanhf(acc);
    }

  } else if (blk < 144){
    const int b = blk - 128;
    float* s_la = shbuf;
    float* s_um = shbuf + 2112;
    float* s_sm = shbuf + 4224;
    float* s_si = shbuf + 6336;
    float* s_or = shbuf + 8448;
    float* s_op = shbuf + 10560;
    #pragma unroll
    for (int p = 0; p < 4; ++p){
      int t = tid + p*512, g = b*T_ + t, ix = idx32(t);
      s_la[ix] = log_anchor[g];
      s_um[ix] = unit_mask[g];
      s_sm[ix] = sealed_mask[g];
      s_si[ix] = silence_mask[g];
    }
    __syncthreads();
    if (tid < 64){
      const float CE = (float)(1.0 - 0.95);
      const int base = tid*32;
      float A = 1.f, Bv = 0.f, S = 0.f;
      for (int j = 0; j < 32; ++j){
        int ix = idx32(base + j);
        float mask   = clamp01(s_um[ix]);
        float sealed = clamp01(s_sm[ix]);
        float sil    = clamp01(s_si[ix])*mask;
        float speech = mask*sealed*(1.f-sil);
        float cm = CE*speech;
        A  = (1.f-cm)*A;
        Bv = (1.f-cm)*Bv + cm*s_la[ix];
        S += speech;
      }
      float Ai=A, Bi=Bv, Si=S;
      for (int off = 1; off < 64; off <<= 1){
        float Ap=__shfl_up(Ai,off), Bp=__shfl_up(Bi,off), Sp=__shfl_up(Si,off);
        if (tid >= off){ Bi = Ai*Bp + Bi; Ai *= Ap; Si += Sp; }
      }
      float Ae=__shfl_up(Ai,1), Be=__shfl_up(Bi,1), Se=__shfl_up(Si,1);
      if (tid==0){ Ae=1.f; Be=0.f; Se=0.f; }
      float r  = Ae*local_rate_ema[b] + Be;
      float ps = Se;
      for (int j = 0; j < 32; ++j){
        int ix = idx32(base + j);
        float mask   = clamp01(s_um[ix]);
        float sealed = clamp01(s_sm[ix]);
        float sil    = clamp01(s_si[ix])*mask;
        float speech = mask*sealed*(1.f-sil);
        s_or[ix] = r;
        s_op[ix] = ps;
        r  += CE*speech*(s_la[ix]-r);
        ps += speech;
      }
    }
    __syncthreads();
    #pragma unroll
    for (int p = 0; p < 4; ++p){
      int t = tid + p*512, g = b*T_ + t, ix = idx32(t);
      lr_seq[g]      = s_or[ix];
      prefix_prev[g] = s_op[ix];
    }

  } else {
    const int kt = blk - 144;
    unsigned short* sb = (unsigned short*)shbuf;   // [32][512]
    #pragma unroll
    for (int p = 0; p < 32; ++p){
      int id = tid + p*512;
      int kl = id >> 9, col = id & 511;
      sb[kl*512 + col] = bf16_rne(rW1[(kt*32 + kl)*512 + col]);
    }
    __syncthreads();
    const int col = tid;
    unsigned q[16];
    #pragma unroll
    for (int p = 0; p < 16; ++p)
      q[p] = (unsigned)sb[(2*p)*512 + col] | ((unsigned)sb[(2*p+1)*512 + col] << 16);
    uint4* dst = (uint4*)(BtG + kt*16384 + col*32);
    dst[0] = make_uint4(q[0], q[1], q[2], q[3]);
    dst[1] = make_uint4(q[4], q[5], q[6], q[7]);
    dst[2] = make_uint4(q[8], q[9], q[10], q[11]);
    dst[3] = make_uint4(q[12], q[13], q[14], q[15]);
  }
}

// ---------------------------------------------------------------------------
// KQ: 1280 blocks x 512 threads.
//  blk 0..1023  : query gen -> Aq[mtile][kt][row128][32] bf16 (GEMM-ready)
//                 unit = blk*512+tid; kt = unit>>15; rr = unit&32767
//  blk 1024..   : old P2 (spk_pb / cpart), bb = blk-1024
// ---------------------------------------------------------------------------
__global__ __launch_bounds__(512) void k_q(
    const int*   __restrict__ content_units, const float* __restrict__ log_anchor,
    const float* __restrict__ unit_mask,     const float* __restrict__ silence_mask,
    const float* __restrict__ sep_hint,      const float* __restrict__ edge_cue,
    const float* __restrict__ embed,         const float* __restrict__ feat_W,
    const float* __restrict__ feat_b,        const float* __restrict__ lr_seq,
    const float* __restrict__ spk_ctx,       const float* __restrict__ global_rate,
    const float* __restrict__ cW1, const float* __restrict__ cb1,
    const float* __restrict__ cW2, const float* __restrict__ rW1,
    const float* __restrict__ rb1,
    unsigned short* __restrict__ Aq,
    float* __restrict__ spk_pb, float* __restrict__ cpart)
{
  __shared__ float sc[512];
  __shared__ float partial[32*64];
  const int tid = threadIdx.x;
  const int blk = blockIdx.x;

  if (blk < 1024){
    const int unit = blk*512 + tid;
    const int kt = unit >> 15;
    const int rr = unit & 32767;
    const float mk = clamp01(unit_mask[rr]);
    const float la = log_anchor[rr];
    const float lr = lr_seq[rr];
    const float si = clamp01(silence_mask[rr])*mk;
    const float sp = sep_hint[rr];
    const float ed = edge_cue[rr];
    const int   u  = content_units[rr];
    const int base = ((rr >> 7)*16 + kt)*4096 + (rr & 127)*32;  // shorts
    #pragma unroll
    for (int c = 0; c < 4; ++c){
      const int jg = kt*32 + c*8;
      float4 w0a = *(const float4*)(feat_W + jg),        w0b = *(const float4*)(feat_W + jg + 4);
      float4 w1a = *(const float4*)(feat_W + 512 + jg),  w1b = *(const float4*)(feat_W + 512 + jg + 4);
      float4 w2a = *(const float4*)(feat_W + 1024 + jg), w2b = *(const float4*)(feat_W + 1024 + jg + 4);
      float4 w3a = *(const float4*)(feat_W + 1536 + jg), w3b = *(const float4*)(feat_W + 1536 + jg + 4);
      float4 w4a = *(const float4*)(feat_W + 2048 + jg), w4b = *(const float4*)(feat_W + 2048 + jg + 4);
      float4 ba  = *(const float4*)(feat_b + jg),        bb4 = *(const float4*)(feat_b + jg + 4);
      const float* eb = embed + (size_t)u*DIM_ + jg;
      float4 ea = *(const float4*)eb, eb4v = *(const float4*)(eb + 4);
      float f0 = ea.x + ba.x + la*w0a.x + lr*w1a.x + si*w2a.x + sp*w3a.x + ed*w4a.x;
      float f1 = ea.y + ba.y + la*w0a.y + lr*w1a.y + si*w2a.y + sp*w3a.y + ed*w4a.y;
      float f2 = ea.z + ba.z + la*w0a.z + lr*w1a.z + si*w2a.z + sp*w3a.z + ed*w4a.z;
      float f3 = ea.w + ba.w + la*w0a.w + lr*w1a.w + si*w2a.w + sp*w3a.w + ed*w4a.w;
      float f4 = eb4v.x + bb4.x + la*w0b.x + lr*w1b.x + si*w2b.x + sp*w3b.x + ed*w4b.x;
      float f5 = eb4v.y + bb4.y + la*w0b.y + lr*w1b.y + si*w2b.y + sp*w3b.y + ed*w4b.y;
      float f6 = eb4v.z + bb4.z + la*w0b.z + lr*w1b.z + si*w2b.z + sp*w3b.z + ed*w4b.z;
      float f7 = eb4v.w + bb4.w + la*w0b.w + lr*w1b.w + si*w2b.w + sp*w3b.w + ed*w4b.w;
      unsigned p0 = cvt_pk_bf16(fast_tanh(f0)*mk, fast_tanh(f1)*mk);
      unsigned p1 = cvt_pk_bf16(fast_tanh(f2)*mk, fast_tanh(f3)*mk);
      unsigned p2 = cvt_pk_bf16(fast_tanh(f4)*mk, fast_tanh(f5)*mk);
      unsigned p3 = cvt_pk_bf16(fast_tanh(f6)*mk, fast_tanh(f7)*mk);
      *(uint4*)&Aq[base + c*8] = make_uint4(p0,p1,p2,p3);
    }

  } else {
    const int bb = blk - 1024;
    const bool isAC = bb >= 128;
    const int bbb = isAC ? (bb - 128) : bb;
    const int b = bbb >> 3, s = bbb & 7, n0 = s*64;

    sc[tid] = spk_ctx[b*512 + tid];
    __syncthreads();
    const int nq = tid & 15, q = tid >> 4;
    const float* mat = isAC ? cW1 : (rW1 + 512*512);
    float a0=0.f, a1=0.f, a2=0.f, a3=0.f;
    const float* wp = mat + (q*16)*512 + n0 + nq*4;
    #pragma unroll
    for (int kk = 0; kk < 16; ++kk){
      float sv = sc[q*16 + kk];
      float4 v = *(const float4*)(wp + kk*512);
      a0 = fmaf(sv, v.x, a0); a1 = fmaf(sv, v.y, a1);
      a2 = fmaf(sv, v.z, a2); a3 = fmaf(sv, v.w, a3);
    }
    *(float4*)&partial[q*64 + nq*4] = make_float4(a0,a1,a2,a3);
    __syncthreads();
    if (tid < 64){
      const int n = n0 + tid;
      float acc = 0.f;
      #pragma unroll
      for (int qq = 0; qq < 32; ++qq) acc += partial[qq*64 + tid];
      if (!isAC){
        spk_pb[b*512 + n] = acc + rb1[n];
      } else {
        float ac = acc + cb1[n] + global_rate[b]*cW1[512*512 + n];
        float g  = gelu_exact(ac)*cW2[n];
        g += __shfl_xor(g,1);  g += __shfl_xor(g,2);  g += __shfl_xor(g,4);
        g += __shfl_xor(g,8);  g += __shfl_xor(g,16); g += __shfl_xor(g,32);
        if (tid == 0) cpart[b*8 + s] = g;
      }
    }
  }
}

// ---------------------------------------------------------------------------
// K_GEMM: pure MFMA kernel (m97 pattern). 256 blocks x 512 thr (8 waves).
// Tile 128 rows x 512 cols; wave (wh=w>>2, wc=w&3) = 64 rows x 128 cols,
// acc[4][8] = 128 AGPR. A and B both staged via global_load_lds, double-
// buffered per kt (8KB + 32KB slabs, linear copies). No VALU A-phase.
// Epilogue: + spk_pb + gt*wb, gelu, dot rW2, final combine.
// ---------------------------------------------------------------------------
__global__ __launch_bounds__(512, 2) void k_gemm(
    const float* __restrict__ log_anchor,    const float* __restrict__ unit_mask,
    const float* __restrict__ sealed_mask,   const float* __restrict__ silence_mask,
    const float* __restrict__ global_rate,
    const float* __restrict__ rW1,           const float* __restrict__ rW2,
    const float* __restrict__ rb2,           const float* __restrict__ cb2,
    const float* __restrict__ lr_seq,        const float* __restrict__ prefix_prev,
    const float* __restrict__ spk_pb,        const float* __restrict__ cpart,
    const unsigned short* __restrict__ Aq,   const unsigned short* __restrict__ BtG,
    float* __restrict__ out)
{
  __shared__ __align__(16) unsigned short As_s[2*4096];    // 16 KB
  __shared__ __align__(16) unsigned short Bs_s[2*16384];   // 64 KB
  __shared__ float r_gt[128], r_speech[128], r_silc[128], r_resmul[128], r_tau[128];
  __shared__ float pdred[4][128];

  const int m0   = blockIdx.x*128;
  const int b    = m0 >> 11;
  const int tid  = threadIdx.x;
  const int lane = tid & 63;
  const int w    = tid >> 6;                // 0..7
  const int wh   = w >> 2, wc = w & 3;
  const int l15  = lane & 15, kg = lane >> 4;

  // ---- stage kt=0 (A: 1 issue, B: 4 issues) into buf 0 ----
  {
    const unsigned short* asrc = Aq + (size_t)blockIdx.x*65536 + tid*8;
    __builtin_amdgcn_global_load_lds(
      (const __attribute__((address_space(1))) unsigned int*)asrc,
      (__attribute__((address_space(3))) unsigned int*)(&As_s[tid*8]), 16, 0, 0);
    #pragma unroll
    for (int i = 0; i < 4; ++i){
      const int chunk = i*8 + w;
      __builtin_amdgcn_global_load_lds(
        (const __attribute__((address_space(1))) unsigned int*)(BtG + chunk*512 + (lane)*8),
        (__attribute__((address_space(3))) unsigned int*)(&Bs_s[chunk*512 + lane*8]), 16, 0, 0);
    }
  }

  if (tid < 128){
    int m = m0 + tid;
    float csum = cb2[0];
    #pragma unroll
    for (int s = 0; s < 8; ++s) csum += cpart[b*8 + s];
    float coarse = 0.2f*tanhf(csum);
    float mask   = clamp01(unit_mask[m]);
    float sealed = clamp01(sealed_mask[m]);
    float sil    = clamp01(silence_mask[m])*mask;
    float commit = mask*sealed;
    float silc   = commit*sil;
    float speech = commit*(1.f-sil);
    float la = log_anchor[m];
    float lr = lr_seq[m];
    float gap = clampf(global_rate[b]-lr, -0.35f, 0.35f)*commit;
    float gt  = (gap + coarse*commit)*commit;
    float cold = clamp01(prefix_prev[m]*0.5f);
    float dur  = expf(la);
    float shortv = clamp01(fmaxf(dur,1.f)-1.f);
    r_gt[tid]=gt; r_speech[tid]=speech; r_silc[tid]=silc;
    r_resmul[tid]=cold*shortv*speech;
    r_tau[tid]=0.35f*((dur<2.0f)?0.35f:1.0f);
  }
  __syncthreads();   // stage(0) + r_* ready

  f32x4 acc[4][8];
  #pragma unroll
  for (int r=0;r<4;++r)
    #pragma unroll
    for (int c=0;c<8;++c) acc[r][c] = (f32x4)0.0f;

  #pragma unroll 4
  for (int kt = 0; kt < 16; ++kt){
    if (kt < 15){
      const int ktn = kt + 1, bn = ktn & 1;
      const unsigned short* asrc = Aq + (size_t)blockIdx.x*65536 + ktn*4096 + tid*8;
      __builtin_amdgcn_global_load_lds(
        (const __attribute__((address_space(1))) unsigned int*)asrc,
        (__attribute__((address_space(3))) unsigned int*)(&As_s[bn*4096 + tid*8]), 16, 0, 0);
      #pragma unroll
      for (int i = 0; i < 4; ++i){
        const int chunk = i*8 + w;
        __builtin_amdgcn_global_load_lds(
          (const __attribute__((address_space(1))) unsigned int*)(BtG + ktn*16384 + chunk*512 + lane*8),
          (__attribute__((address_space(3))) unsigned int*)(&Bs_s[bn*16384 + chunk*512 + lane*8]), 16, 0, 0);
      }
    }
    const int bc = kt & 1;
    short8_t af[4], bfr[8];
    #pragma unroll
    for (int r=0;r<4;++r)
      af[r] = *(const short8_t*)&As_s[bc*4096 + (wh*64 + r*16 + l15)*32 + kg*8];
    #pragma unroll
    for (int c=0;c<8;++c)
      bfr[c] = *(const short8_t*)&Bs_s[bc*16384 + (wc*128 + c*16 + l15)*32 + kg*8];
    #pragma unroll
    for (int r=0;r<4;++r)
      #pragma unroll
      for (int c=0;c<8;++c)
        acc[r][c] = __builtin_amdgcn_mfma_f32_16x16x32_bf16(af[r], bfr[c], acc[r][c], 0, 0, 0);
    __syncthreads();
  }

  // --- epilogue: x = acc + spk_pb[col] + gt[row]*wb[col]; gelu; dot rW2 ---
  const int colb = wc*128 + l15;
  float stv[8], wbv[8], w2v[8];
  #pragma unroll
  for (int c=0;c<8;++c){
    int col = colb + c*16;
    stv[c] = spk_pb[b*DIM_ + col];
    wbv[c] = rW1[1024*DIM_ + col];
    w2v[c] = rW2[col];
  }
  #pragma unroll
  for (int r=0;r<4;++r){
    #pragma unroll
    for (int g=0; g<4; ++g){
      int lrow = wh*64 + r*16 + kg*4 + g;  // C/D: row=(lane>>4)*4+reg
      float gt = r_gt[lrow];
      float s = 0.f;
      #pragma unroll
      for (int c=0;c<8;++c){
        float x = acc[r][c][g] + stv[c] + gt*wbv[c];
        s += gelu_fast(x)*w2v[c];
      }
      s += __shfl_xor(s,1); s += __shfl_xor(s,2);
      s += __shfl_xor(s,4); s += __shfl_xor(s,8);
      if (l15 == 0) pdred[wc][lrow] = s;
    }
  }
  __syncthreads();
  if (tid < 128){
    float v = rb2[0] + pdred[0][tid] + pdred[1][tid] + pdred[2][tid] + pdred[3][tid];
    float residual = 0.35f*tanhf(v) * r_resmul[tid];
    float gt = r_gt[tid];
    out[m0+tid] = clampf(gt + residual, -1.2f, 1.2f)*r_speech[tid]
                + clampf(gt, -r_tau[tid], r_tau[tid])*r_silc[tid];
  }
}

// ---------------------------------------------------------------------------
extern "C" void kernel_launch(void* const* d_in, const int* in_sizes, int n_in,
                              void* d_out, int out_size, void* d_ws, size_t ws_size,
                              hipStream_t stream)
{
  const int*   content_units  = (const int*)  d_in[0];
  const float* log_anchor     = (const float*)d_in[1];
  const float* unit_mask      = (const float*)d_in[2];
  const float* sealed_mask    = (const float*)d_in[3];
  const float* sep_hint       = (const float*)d_in[4];
  const float* edge_cue       = (const float*)d_in[5];
  const float* global_rate    = (const float*)d_in[6];
  const float* local_rate_ema = (const float*)d_in[7];
  const float* silence_mask   = (const float*)d_in[8];
  const float* spk_embed      = (const float*)d_in[9];
  const float* embed          = (const float*)d_in[10];
  const float* feat_W         = (const float*)d_in[11];
  const float* feat_b         = (const float*)d_in[12];
  const float* spk_W          = (const float*)d_in[13];
  const float* spk_b          = (const float*)d_in[14];
  const float* cW1            = (const float*)d_in[15];
  const float* cb1            = (const float*)d_in[16];
  const float* cW2            = (const float*)d_in[17];
  const float* cb2            = (const float*)d_in[18];
  const float* rW1            = (const float*)d_in[19];
  const float* rb1            = (const float*)d_in[20];
  const float* rW2            = (const float*)d_in[21];
  const float* rb2            = (const float*)d_in[22];
  float* out = (float*)d_out;

  // ws (floats): lr_seq 32768 | prefix 32768 | spk_ctx 8192 | spk_pb 8192 |
  // cpart 128 | BtG bf16 512KB (262144 shorts) | Aq bf16 33.55MB.
  float* ws       = (float*)d_ws;
  float* lr_seq   = ws;
  float* prefix   = ws + 32768;
  float* spk_ctx  = ws + 65536;
  float* spk_pb   = ws + 73728;
  float* cpart    = ws + 81920;
  unsigned short* BtG = (unsigned short*)(ws + 82048);
  unsigned short* Aq  = BtG + 262144;

  k_p1<<<160, 512, 0, stream>>>(log_anchor, unit_mask, sealed_mask, silence_mask,
                                local_rate_ema, spk_embed, spk_W, spk_b, rW1,
                                lr_seq, prefix, spk_ctx, BtG);
  k_q<<<1280, 512, 0, stream>>>(content_units, log_anchor, unit_mask, silence_mask,
                                sep_hint, edge_cue, embed, feat_W, feat_b, lr_seq,
                                spk_ctx, global_rate, cW1, cb1, cW2, rW1, rb1,
                                Aq, spk_pb, cpart);
  k_gemm<<<M_/128, 512, 0, stream>>>(log_anchor, unit_mask, sealed_mask, silence_mask,
                                     global_rate, rW1, rW2, rb2, cb2,
                                     lr_seq, prefix, spk_pb, cpart, Aq, BtG, out);
}

// Round 10
// 56.386 us; speedup vs baseline: 1.3109x; 1.3109x over previous
//
#include <hip/hip_runtime.h>
#include <math.h>

#define B_    16
#define T_    2048
#define DIM_  512
#define M_    (B_*T_)
#define ASP   264     // A LDS row stride in shorts (528B): 16B-aligned, 2-way bank (free)
#define BCS   40      // B col stride in shorts (80B): 16B-aligned, 2-way bank (free)
#define BSLAB 20480   // shorts per kt slab: 512 cols * 40

typedef __attribute__((ext_vector_type(8))) short short8_t;   // 8 x bf16 bits
typedef __attribute__((ext_vector_type(4))) float f32x4;

__device__ __forceinline__ float clamp01(float x){ return fminf(fmaxf(x,0.f),1.f); }
__device__ __forceinline__ float clampf(float x,float lo,float hi){ return fminf(fmaxf(x,lo),hi); }
__device__ __forceinline__ float gelu_exact(float x){ return 0.5f*x*(1.f+erff(x*0.70710678118654752f)); }
__device__ __forceinline__ unsigned short bf16_rne(float f){
  unsigned u = __float_as_uint(f);
  unsigned r = (u + 0x7fffu + ((u>>16)&1u)) >> 16;
  return (unsigned short)r;
}
__device__ __forceinline__ float fast_tanh(float x){
  float e = __expf(2.0f*x);
  return 1.0f - 2.0f*__builtin_amdgcn_rcpf(e + 1.0f);
}
// tanh-form GELU (max abs dev ~3e-4; epilogue only)
__device__ __forceinline__ float gelu_fast(float x){
  float u = 0.7978845608028654f*fmaf(0.044715f*x, x*x, x);
  return 0.5f*x*(1.f + fast_tanh(u));
}
__device__ __forceinline__ unsigned cvt_pk_bf16(float lo, float hi){
  unsigned r;
  asm("v_cvt_pk_bf16_f32 %0, %1, %2" : "=v"(r) : "v"(lo), "v"(hi));
  return r;
}
__device__ __forceinline__ int idx32(int t){ return t + (t>>5); }  // pad stride 33

// ---------------------------------------------------------------------------
// P1: 160 blocks x 512 threads.
//  blk   0..127 : spk_ctx[b, s*64 .. s*64+64)  (b=blk>>3, s=blk&7)
//  blk 128..143 : EMA scan + excl cumsum       (b=blk-128)
//  blk 144..159 : rW1[0:512] -> bf16 Bt[kt][col][40-pad]  (kt=blk-144)
// ---------------------------------------------------------------------------
__global__ __launch_bounds__(512) void k_p1(
    const float* __restrict__ log_anchor, const float* __restrict__ unit_mask,
    const float* __restrict__ sealed_mask, const float* __restrict__ silence_mask,
    const float* __restrict__ local_rate_ema,
    const float* __restrict__ spk_embed, const float* __restrict__ spk_W,
    const float* __restrict__ spk_b, const float* __restrict__ rW1,
    float* __restrict__ lr_seq, float* __restrict__ prefix_prev,
    float* __restrict__ spk_ctx, unsigned short* __restrict__ BtG)
{
  __shared__ float shbuf[12672];
  const int tid = threadIdx.x;
  const int blk = blockIdx.x;

  if (blk < 128){
    const int b = blk >> 3, n0 = (blk & 7)*64;
    float* se      = shbuf;
    float* partial = shbuf + 512;
    se[tid] = spk_embed[b*512 + tid];
    __syncthreads();
    const int nq = tid & 15, q = tid >> 4;
    float a0=0.f, a1=0.f, a2=0.f, a3=0.f;
    const float* wp = spk_W + (q*16)*512 + n0 + nq*4;
    #pragma unroll
    for (int kk = 0; kk < 16; ++kk){
      float s = se[q*16 + kk];
      float4 v = *(const float4*)(wp + kk*512);
      a0 = fmaf(s, v.x, a0); a1 = fmaf(s, v.y, a1);
      a2 = fmaf(s, v.z, a2); a3 = fmaf(s, v.w, a3);
    }
    *(float4*)&partial[q*64 + nq*4] = make_float4(a0,a1,a2,a3);
    __syncthreads();
    if (tid < 64){
      float acc = spk_b[n0 + tid];
      #pragma unroll
      for (int qq = 0; qq < 32; ++qq) acc += partial[qq*64 + tid];
      spk_ctx[b*512 + n0 + tid] = tanhf(acc);
    }

  } else if (blk < 144){
    const int b = blk - 128;
    float* s_la = shbuf;
    float* s_um = shbuf + 2112;
    float* s_sm = shbuf + 4224;
    float* s_si = shbuf + 6336;
    float* s_or = shbuf + 8448;
    float* s_op = shbuf + 10560;
    #pragma unroll
    for (int p = 0; p < 4; ++p){
      int t = tid + p*512, g = b*T_ + t, ix = idx32(t);
      s_la[ix] = log_anchor[g];
      s_um[ix] = unit_mask[g];
      s_sm[ix] = sealed_mask[g];
      s_si[ix] = silence_mask[g];
    }
    __syncthreads();
    if (tid < 64){
      const float CE = (float)(1.0 - 0.95);
      const int base = tid*32;
      float A = 1.f, Bv = 0.f, S = 0.f;
      for (int j = 0; j < 32; ++j){
        int ix = idx32(base + j);
        float mask   = clamp01(s_um[ix]);
        float sealed = clamp01(s_sm[ix]);
        float sil    = clamp01(s_si[ix])*mask;
        float speech = mask*sealed*(1.f-sil);
        float cm = CE*speech;
        A  = (1.f-cm)*A;
        Bv = (1.f-cm)*Bv + cm*s_la[ix];
        S += speech;
      }
      float Ai=A, Bi=Bv, Si=S;
      for (int off = 1; off < 64; off <<= 1){
        float Ap=__shfl_up(Ai,off), Bp=__shfl_up(Bi,off), Sp=__shfl_up(Si,off);
        if (tid >= off){ Bi = Ai*Bp + Bi; Ai *= Ap; Si += Sp; }
      }
      float Ae=__shfl_up(Ai,1), Be=__shfl_up(Bi,1), Se=__shfl_up(Si,1);
      if (tid==0){ Ae=1.f; Be=0.f; Se=0.f; }
      float r  = Ae*local_rate_ema[b] + Be;
      float ps = Se;
      for (int j = 0; j < 32; ++j){
        int ix = idx32(base + j);
        float mask   = clamp01(s_um[ix]);
        float sealed = clamp01(s_sm[ix]);
        float sil    = clamp01(s_si[ix])*mask;
        float speech = mask*sealed*(1.f-sil);
        s_or[ix] = r;
        s_op[ix] = ps;
        r  += CE*speech*(s_la[ix]-r);
        ps += speech;
      }
    }
    __syncthreads();
    #pragma unroll
    for (int p = 0; p < 4; ++p){
      int t = tid + p*512, g = b*T_ + t, ix = idx32(t);
      lr_seq[g]      = s_or[ix];
      prefix_prev[g] = s_op[ix];
    }

  } else {
    const int kt = blk - 144;
    unsigned short* sb = (unsigned short*)shbuf;   // [32][512]
    #pragma unroll
    for (int p = 0; p < 32; ++p){
      int id = tid + p*512;
      int kl = id >> 9, col = id & 511;
      sb[kl*512 + col] = bf16_rne(rW1[(kt*32 + kl)*512 + col]);
    }
    __syncthreads();
    const int col = tid;
    unsigned q[16];
    #pragma unroll
    for (int p = 0; p < 16; ++p)
      q[p] = (unsigned)sb[(2*p)*512 + col] | ((unsigned)sb[(2*p+1)*512 + col] << 16);
    uint4* dst = (uint4*)(BtG + kt*BSLAB + col*BCS);   // 80B rows (16B pad unused)
    dst[0] = make_uint4(q[0], q[1], q[2], q[3]);
    dst[1] = make_uint4(q[4], q[5], q[6], q[7]);
    dst[2] = make_uint4(q[8], q[9], q[10], q[11]);
    dst[3] = make_uint4(q[12], q[13], q[14], q[15]);
  }
}

// ---------------------------------------------------------------------------
// P2: 256 blocks x 512 threads.
//  blk   0..127 : spk_pb[b, slice] = sc@rW1[512:1024,slice] + rb1
//  blk 128..255 : cpart[b][s] = sum_slice gelu(ac)*cW2   (coarse partials)
// ---------------------------------------------------------------------------
__global__ __launch_bounds__(512) void k_p2(
    const float* __restrict__ spk_ctx, const float* __restrict__ global_rate,
    const float* __restrict__ cW1, const float* __restrict__ cb1,
    const float* __restrict__ cW2, const float* __restrict__ rW1,
    const float* __restrict__ rb1,
    float* __restrict__ spk_pb, float* __restrict__ cpart)
{
  __shared__ float sc[512];
  __shared__ float partial[32*64];
  const int tid = threadIdx.x;
  const int blk = blockIdx.x;
  const bool isAC = blk >= 128;
  const int bb = isAC ? (blk - 128) : blk;
  const int b = bb >> 3, s = bb & 7, n0 = s*64;

  sc[tid] = spk_ctx[b*512 + tid];
  __syncthreads();
  const int nq = tid & 15, q = tid >> 4;
  const float* mat = isAC ? cW1 : (rW1 + 512*512);
  float a0=0.f, a1=0.f, a2=0.f, a3=0.f;
  const float* wp = mat + (q*16)*512 + n0 + nq*4;
  #pragma unroll
  for (int kk = 0; kk < 16; ++kk){
    float sv = sc[q*16 + kk];
    float4 v = *(const float4*)(wp + kk*512);
    a0 = fmaf(sv, v.x, a0); a1 = fmaf(sv, v.y, a1);
    a2 = fmaf(sv, v.z, a2); a3 = fmaf(sv, v.w, a3);
  }
  *(float4*)&partial[q*64 + nq*4] = make_float4(a0,a1,a2,a3);
  __syncthreads();
  if (tid < 64){
    const int n = n0 + tid;
    float acc = 0.f;
    #pragma unroll
    for (int qq = 0; qq < 32; ++qq) acc += partial[qq*64 + tid];
    if (!isAC){
      spk_pb[b*512 + n] = acc + rb1[n];
    } else {
      float ac = acc + cb1[n] + global_rate[b]*cW1[512*512 + n];
      float g  = gelu_exact(ac)*cW2[n];
      g += __shfl_xor(g,1);  g += __shfl_xor(g,2);  g += __shfl_xor(g,4);
      g += __shfl_xor(g,8);  g += __shfl_xor(g,16); g += __shfl_xor(g,32);
      if (tid == 0) cpart[b*8 + s] = g;
    }
  }
}

// ---------------------------------------------------------------------------
// K3: fused MFMA kernel with T4 counted-vmcnt pipeline.
// 256 blocks x 512 thr (8 waves), tile 128 rows x 512 cols, acc[4][8].
// Per kt: {issue stage(kt+1) [5 gload_lds] ; s_waitcnt vmcnt(5) ; s_barrier ;
//          ds_read + 32 MFMA (setprio) ; s_barrier}.
// Never drains vmcnt to 0 in the loop (vs r8's __syncthreads = 16 full drains).
// A computed in 2 half-K phases (lgkmcnt(0)+barrier only — no vmcnt drain).
// ---------------------------------------------------------------------------
__global__ __launch_bounds__(512, 2) void k_heavy(
    const int*   __restrict__ content_units, const float* __restrict__ log_anchor,
    const float* __restrict__ unit_mask,     const float* __restrict__ sealed_mask,
    const float* __restrict__ sep_hint,      const float* __restrict__ edge_cue,
    const float* __restrict__ global_rate,   const float* __restrict__ silence_mask,
    const float* __restrict__ embed,         const float* __restrict__ feat_W,
    const float* __restrict__ feat_b,        const float* __restrict__ rW1,
    const float* __restrict__ rW2,           const float* __restrict__ rb2,
    const float* __restrict__ cb2,
    const float* __restrict__ lr_seq,        const float* __restrict__ prefix_prev,
    const float* __restrict__ spk_pb,        const float* __restrict__ cpart,
    const unsigned short* __restrict__ BtG,
    float* __restrict__ out)
{
  __shared__ __align__(16) unsigned short As_s[128*ASP];   // 67584 B
  __shared__ __align__(16) unsigned short Bs_s[2*BSLAB];   // 81920 B
  __shared__ float r_la[128], r_lr[128], r_sil[128], r_sep[128], r_edge[128], r_mask[128];
  __shared__ int   r_u[128];
  __shared__ float r_gt[128], r_speech[128], r_silc[128], r_resmul[128], r_tau[128];
  __shared__ float pdred[4][128];

  const int m0   = blockIdx.x*128;
  const int b    = m0 >> 11;
  const int tid  = threadIdx.x;
  const int lane = tid & 63;
  const int w    = tid >> 6;                // 0..7
  const int wh   = w >> 2, wc = w & 3;
  const int l15  = lane & 15, kg = lane >> 4;

  // ---- stage kt=0 into buf0 (in flight across the prologue) ----
  {
    const unsigned short* src = BtG + w*2560 + lane*8;
    #pragma unroll
    for (int i = 0; i < 5; ++i)
      __builtin_amdgcn_global_load_lds(
        (const __attribute__((address_space(1))) unsigned int*)(src + i*512),
        (__attribute__((address_space(3))) unsigned int*)(&Bs_s[w*2560 + i*512]),
        16, 0, 0);
  }

  if (tid < 128){
    int m = m0 + tid;
    float csum = cb2[0];
    #pragma unroll
    for (int s = 0; s < 8; ++s) csum += cpart[b*8 + s];
    float coarse = 0.2f*tanhf(csum);
    float mask   = clamp01(unit_mask[m]);
    float sealed = clamp01(sealed_mask[m]);
    float sil    = clamp01(silence_mask[m])*mask;
    float commit = mask*sealed;
    float silc   = commit*sil;
    float speech = commit*(1.f-sil);
    float la = log_anchor[m];
    float lr = lr_seq[m];
    float gap = clampf(global_rate[b]-lr, -0.35f, 0.35f)*commit;
    float gt  = (gap + coarse*commit)*commit;
    float cold = clamp01(prefix_prev[m]*0.5f);
    float dur  = expf(la);
    float shortv = clamp01(fmaxf(dur,1.f)-1.f);
    r_la[tid]=la; r_lr[tid]=lr; r_sil[tid]=sil;
    r_sep[tid]=sep_hint[m]; r_edge[tid]=edge_cue[m]; r_mask[tid]=mask;
    r_u[tid]=content_units[m];
    r_gt[tid]=gt; r_speech[tid]=speech; r_silc[tid]=silc;
    r_resmul[tid]=cold*shortv*speech;
    r_tau[tid]=0.35f*((dur<2.0f)?0.35f:1.0f);
  }
  __syncthreads();   // r_* visible (also drains stage(0) — prologue only, fine)

  f32x4 acc[4][8];
  #pragma unroll
  for (int r=0;r<4;++r)
    #pragma unroll
    for (int c=0;c<8;++c) acc[r][c] = (f32x4)0.0f;

  const int rowg = tid >> 4, ksl = tid & 15;    // A-compute: 4 rows x 16 k

  // ================= A half 0 =================
  #pragma unroll
  for (int c8 = 0; c8 < 2; ++c8){
    const int jg = ksl*16 + c8*8;
    float4 w0a = *(const float4*)(feat_W + jg),        w0b = *(const float4*)(feat_W + jg + 4);
    float4 w1a = *(const float4*)(feat_W + 512 + jg),  w1b = *(const float4*)(feat_W + 512 + jg + 4);
    float4 w2a = *(const float4*)(feat_W + 1024 + jg), w2b = *(const float4*)(feat_W + 1024 + jg + 4);
    float4 w3a = *(const float4*)(feat_W + 1536 + jg), w3b = *(const float4*)(feat_W + 1536 + jg + 4);
    float4 w4a = *(const float4*)(feat_W + 2048 + jg), w4b = *(const float4*)(feat_W + 2048 + jg + 4);
    float4 ba  = *(const float4*)(feat_b + jg),        bb4 = *(const float4*)(feat_b + jg + 4);
    #pragma unroll
    for (int i = 0; i < 4; ++i){
      const int row = rowg*4 + i;
      const int u = r_u[row];
      const float la=r_la[row], lr=r_lr[row], si=r_sil[row],
                  sp=r_sep[row], ed=r_edge[row], mk=r_mask[row];
      const float* eb = embed + (size_t)u*DIM_ + jg;
      float4 ea = *(const float4*)eb, eb4v = *(const float4*)(eb + 4);
      float f0 = ea.x + ba.x + la*w0a.x + lr*w1a.x + si*w2a.x + sp*w3a.x + ed*w4a.x;
      float f1 = ea.y + ba.y + la*w0a.y + lr*w1a.y + si*w2a.y + sp*w3a.y + ed*w4a.y;
      float f2 = ea.z + ba.z + la*w0a.z + lr*w1a.z + si*w2a.z + sp*w3a.z + ed*w4a.z;
      float f3 = ea.w + ba.w + la*w0a.w + lr*w1a.w + si*w2a.w + sp*w3a.w + ed*w4a.w;
      float f4 = eb4v.x + bb4.x + la*w0b.x + lr*w1b.x + si*w2b.x + sp*w3b.x + ed*w4b.x;
      float f5 = eb4v.y + bb4.y + la*w0b.y + lr*w1b.y + si*w2b.y + sp*w3b.y + ed*w4b.y;
      float f6 = eb4v.z + bb4.z + la*w0b.z + lr*w1b.z + si*w2b.z + sp*w3b.z + ed*w4b.z;
      float f7 = eb4v.w + bb4.w + la*w0b.w + lr*w1b.w + si*w2b.w + sp*w3b.w + ed*w4b.w;
      unsigned p0 = cvt_pk_bf16(fast_tanh(f0)*mk, fast_tanh(f1)*mk);
      unsigned p1 = cvt_pk_bf16(fast_tanh(f2)*mk, fast_tanh(f3)*mk);
      unsigned p2 = cvt_pk_bf16(fast_tanh(f4)*mk, fast_tanh(f5)*mk);
      unsigned p3 = cvt_pk_bf16(fast_tanh(f6)*mk, fast_tanh(f7)*mk);
      *(uint4*)&As_s[row*ASP + ksl*16 + c8*8] = make_uint4(p0,p1,p2,p3);
    }
  }
  asm volatile("s_waitcnt lgkmcnt(0)" ::: "memory");   // A writes landed
  __builtin_amdgcn_s_barrier();                        // (stage(0) drained earlier)

  // ================= kt 0..7 : counted-vmcnt pipeline =================
  #pragma unroll
  for (int kt = 0; kt < 8; ++kt){
    {  // stage kt+1 -> buf (kt+1)&1
      const int ktn = kt + 1;
      const unsigned short* src = BtG + ktn*BSLAB + w*2560 + lane*8;
      #pragma unroll
      for (int i = 0; i < 5; ++i)
        __builtin_amdgcn_global_load_lds(
          (const __attribute__((address_space(1))) unsigned int*)(src + i*512),
          (__attribute__((address_space(3))) unsigned int*)(&Bs_s[(ktn&1)*BSLAB + w*2560 + i*512]),
          16, 0, 0);
    }
    asm volatile("s_waitcnt vmcnt(5)" ::: "memory");   // kt's 5 landed; kt+1 in flight
    __builtin_amdgcn_s_barrier();                      // all waves: kt data ready
    short8_t af[4], bfr[8];
    #pragma unroll
    for (int r=0;r<4;++r)
      af[r] = *(const short8_t*)&As_s[(wh*64 + r*16 + l15)*ASP + kt*32 + kg*8];
    #pragma unroll
    for (int c=0;c<8;++c)
      bfr[c] = *(const short8_t*)&Bs_s[(kt&1)*BSLAB + (wc*128 + c*16 + l15)*BCS + kg*8];
    __builtin_amdgcn_s_setprio(1);
    #pragma unroll
    for (int r=0;r<4;++r)
      #pragma unroll
      for (int c=0;c<8;++c)
        acc[r][c] = __builtin_amdgcn_mfma_f32_16x16x32_bf16(af[r], bfr[c], acc[r][c], 0, 0, 0);
    __builtin_amdgcn_s_setprio(0);
    __builtin_amdgcn_s_barrier();                      // buf(kt) reads done -> reusable
  }

  // ================= A half 1 (stage(8) stays in flight) =================
  #pragma unroll
  for (int c8 = 0; c8 < 2; ++c8){
    const int jg = 256 + ksl*16 + c8*8;
    float4 w0a = *(const float4*)(feat_W + jg),        w0b = *(const float4*)(feat_W + jg + 4);
    float4 w1a = *(const float4*)(feat_W + 512 + jg),  w1b = *(const float4*)(feat_W + 512 + jg + 4);
    float4 w2a = *(const float4*)(feat_W + 1024 + jg), w2b = *(const float4*)(feat_W + 1024 + jg + 4);
    float4 w3a = *(const float4*)(feat_W + 1536 + jg), w3b = *(const float4*)(feat_W + 1536 + jg + 4);
    float4 w4a = *(const float4*)(feat_W + 2048 + jg), w4b = *(const float4*)(feat_W + 2048 + jg + 4);
    float4 ba  = *(const float4*)(feat_b + jg),        bb4 = *(const float4*)(feat_b + jg + 4);
    #pragma unroll
    for (int i = 0; i < 4; ++i){
      const int row = rowg*4 + i;
      const int u = r_u[row];
      const float la=r_la[row], lr=r_lr[row], si=r_sil[row],
                  sp=r_sep[row], ed=r_edge[row], mk=r_mask[row];
      const float* eb = embed + (size_t)u*DIM_ + jg;
      float4 ea = *(const float4*)eb, eb4v = *(const float4*)(eb + 4);
      float f0 = ea.x + ba.x + la*w0a.x + lr*w1a.x + si*w2a.x + sp*w3a.x + ed*w4a.x;
      float f1 = ea.y + ba.y + la*w0a.y + lr*w1a.y + si*w2a.y + sp*w3a.y + ed*w4a.y;
      float f2 = ea.z + ba.z + la*w0a.z + lr*w1a.z + si*w2a.z + sp*w3a.z + ed*w4a.z;
      float f3 = ea.w + ba.w + la*w0a.w + lr*w1a.w + si*w2a.w + sp*w3a.w + ed*w4a.w;
      float f4 = eb4v.x + bb4.x + la*w0b.x + lr*w1b.x + si*w2b.x + sp*w3b.x + ed*w4b.x;
      float f5 = eb4v.y + bb4.y + la*w0b.y + lr*w1b.y + si*w2b.y + sp*w3b.y + ed*w4b.y;
      float f6 = eb4v.z + bb4.z + la*w0b.z + lr*w1b.z + si*w2b.z + sp*w3b.z + ed*w4b.z;
      float f7 = eb4v.w + bb4.w + la*w0b.w + lr*w1b.w + si*w2b.w + sp*w3b.w + ed*w4b.w;
      unsigned p0 = cvt_pk_bf16(fast_tanh(f0)*mk, fast_tanh(f1)*mk);
      unsigned p1 = cvt_pk_bf16(fast_tanh(f2)*mk, fast_tanh(f3)*mk);
      unsigned p2 = cvt_pk_bf16(fast_tanh(f4)*mk, fast_tanh(f5)*mk);
      unsigned p3 = cvt_pk_bf16(fast_tanh(f6)*mk, fast_tanh(f7)*mk);
      *(uint4*)&As_s[row*ASP + ksl*16 + c8*8] = make_uint4(p0,p1,p2,p3);
    }
  }
  asm volatile("s_waitcnt lgkmcnt(0)" ::: "memory");
  __builtin_amdgcn_s_barrier();

  // ================= kt 8..15 =================
  #pragma unroll
  for (int kt = 8; kt < 16; ++kt){
    if (kt < 15){
      const int ktn = kt + 1;
      const unsigned short* src = BtG + ktn*BSLAB + w*2560 + lane*8;
      #pragma unroll
      for (int i = 0; i < 5; ++i)
        __builtin_amdgcn_global_load_lds(
          (const __attribute__((address_space(1))) unsigned int*)(src + i*512),
          (__attribute__((address_space(3))) unsigned int*)(&Bs_s[(ktn&1)*BSLAB + w*2560 + i*512]),
          16, 0, 0);
      asm volatile("s_waitcnt vmcnt(5)" ::: "memory");
    } else {
      asm volatile("s_waitcnt vmcnt(0)" ::: "memory");
    }
    __builtin_amdgcn_s_barrier();
    short8_t af[4], bfr[8];
    #pragma unroll
    for (int r=0;r<4;++r)
      af[r] = *(const short8_t*)&As_s[(wh*64 + r*16 + l15)*ASP + (kt-8)*32 + kg*8];
    #pragma unroll
    for (int c=0;c<8;++c)
      bfr[c] = *(const short8_t*)&Bs_s[(kt&1)*BSLAB + (wc*128 + c*16 + l15)*BCS + kg*8];
    __builtin_amdgcn_s_setprio(1);
    #pragma unroll
    for (int r=0;r<4;++r)
      #pragma unroll
      for (int c=0;c<8;++c)
        acc[r][c] = __builtin_amdgcn_mfma_f32_16x16x32_bf16(af[r], bfr[c], acc[r][c], 0, 0, 0);
    __builtin_amdgcn_s_setprio(0);
    __builtin_amdgcn_s_barrier();
  }

  // --- epilogue: x = acc + spk_pb[col] + gt[row]*wb[col]; gelu; dot rW2 ---
  const int colb = wc*128 + l15;
  float stv[8], wbv[8], w2v[8];
  #pragma unroll
  for (int c=0;c<8;++c){
    int col = colb + c*16;
    stv[c] = spk_pb[b*DIM_ + col];
    wbv[c] = rW1[1024*DIM_ + col];
    w2v[c] = rW2[col];
  }
  #pragma unroll
  for (int r=0;r<4;++r){
    #pragma unroll
    for (int g=0; g<4; ++g){
      int lrow = wh*64 + r*16 + kg*4 + g;  // C/D: row=(lane>>4)*4+reg
      float gt = r_gt[lrow];
      float s = 0.f;
      #pragma unroll
      for (int c=0;c<8;++c){
        float x = acc[r][c][g] + stv[c] + gt*wbv[c];
        s += gelu_fast(x)*w2v[c];
      }
      s += __shfl_xor(s,1); s += __shfl_xor(s,2);
      s += __shfl_xor(s,4); s += __shfl_xor(s,8);
      if (l15 == 0) pdred[wc][lrow] = s;
    }
  }
  __syncthreads();
  if (tid < 128){
    float v = rb2[0] + pdred[0][tid] + pdred[1][tid] + pdred[2][tid] + pdred[3][tid];
    float residual = 0.35f*tanhf(v) * r_resmul[tid];
    float gt = r_gt[tid];
    out[m0+tid] = clampf(gt + residual, -1.2f, 1.2f)*r_speech[tid]
                + clampf(gt, -r_tau[tid], r_tau[tid])*r_silc[tid];
  }
}

// ---------------------------------------------------------------------------
extern "C" void kernel_launch(void* const* d_in, const int* in_sizes, int n_in,
                              void* d_out, int out_size, void* d_ws, size_t ws_size,
                              hipStream_t stream)
{
  const int*   content_units  = (const int*)  d_in[0];
  const float* log_anchor     = (const float*)d_in[1];
  const float* unit_mask      = (const float*)d_in[2];
  const float* sealed_mask    = (const float*)d_in[3];
  const float* sep_hint       = (const float*)d_in[4];
  const float* edge_cue       = (const float*)d_in[5];
  const float* global_rate    = (const float*)d_in[6];
  const float* local_rate_ema = (const float*)d_in[7];
  const float* silence_mask   = (const float*)d_in[8];
  const float* spk_embed      = (const float*)d_in[9];
  const float* embed          = (const float*)d_in[10];
  const float* feat_W         = (const float*)d_in[11];
  const float* feat_b         = (const float*)d_in[12];
  const float* spk_W          = (const float*)d_in[13];
  const float* spk_b          = (const float*)d_in[14];
  const float* cW1            = (const float*)d_in[15];
  const float* cb1            = (const float*)d_in[16];
  const float* cW2            = (const float*)d_in[17];
  const float* cb2            = (const float*)d_in[18];
  const float* rW1            = (const float*)d_in[19];
  const float* rb1            = (const float*)d_in[20];
  const float* rW2            = (const float*)d_in[21];
  const float* rb2            = (const float*)d_in[22];
  float* out = (float*)d_out;

  float* ws       = (float*)d_ws;
  float* lr_seq   = ws;                  // 32768
  float* prefix   = ws + 32768;          // 32768
  float* spk_ctx  = ws + 65536;          // 8192
  float* spk_pb   = ws + 73728;          // 8192
  float* cpart    = ws + 81920;          // 128
  unsigned short* BtG = (unsigned short*)(ws + 82048);   // 16*20480 shorts = 640 KB

  k_p1<<<160, 512, 0, stream>>>(log_anchor, unit_mask, sealed_mask, silence_mask,
                                local_rate_ema, spk_embed, spk_W, spk_b, rW1,
                                lr_seq, prefix, spk_ctx, BtG);
  k_p2<<<256, 512, 0, stream>>>(spk_ctx, global_rate, cW1, cb1, cW2, rW1, rb1,
                                spk_pb, cpart);
  k_heavy<<<M_/128, 512, 0, stream>>>(content_units, log_anchor, unit_mask, sealed_mask,
                                      sep_hint, edge_cue, global_rate, silence_mask,
                                      embed, feat_W, feat_b, rW1, rW2, rb2, cb2,
                                      lr_seq, prefix, spk_pb, cpart, BtG, out);
}

// Round 11
// 52.508 us; speedup vs baseline: 1.4078x; 1.0739x over previous
//
#include <hip/hip_runtime.h>
#include <math.h>

#define B_    16
#define T_    2048
#define DIM_  512
#define M_    (B_*T_)
#define ASP   520     // A LDS row stride in shorts (1040 B)

typedef __attribute__((ext_vector_type(8))) short short8_t;   // 8 x bf16 bits
typedef __attribute__((ext_vector_type(4))) float f32x4;

__device__ __forceinline__ float clamp01(float x){ return fminf(fmaxf(x,0.f),1.f); }
__device__ __forceinline__ float clampf(float x,float lo,float hi){ return fminf(fmaxf(x,lo),hi); }
__device__ __forceinline__ float gelu_exact(float x){ return 0.5f*x*(1.f+erff(x*0.70710678118654752f)); }
__device__ __forceinline__ unsigned short bf16_rne(float f){
  unsigned u = __float_as_uint(f);
  unsigned r = (u + 0x7fffu + ((u>>16)&1u)) >> 16;
  return (unsigned short)r;
}
__device__ __forceinline__ float fast_tanh(float x){
  float e = __expf(2.0f*x);
  return 1.0f - 2.0f*__builtin_amdgcn_rcpf(e + 1.0f);
}
// tanh-form GELU (max abs dev ~3e-4; epilogue only)
__device__ __forceinline__ float gelu_fast(float x){
  float u = 0.7978845608028654f*fmaf(0.044715f*x, x*x, x);
  return 0.5f*x*(1.f + fast_tanh(u));
}
__device__ __forceinline__ unsigned cvt_pk_bf16(float lo, float hi){
  unsigned r;
  asm("v_cvt_pk_bf16_f32 %0, %1, %2" : "=v"(r) : "v"(lo), "v"(hi));
  return r;
}
__device__ __forceinline__ int idx32(int t){ return t + (t>>5); }  // pad stride 33

// ---------------------------------------------------------------------------
// P1: 160 blocks x 512 threads.
//  blk   0..127 : spk_ctx[b, s*64 .. s*64+64)  (b=blk>>3, s=blk&7)
//  blk 128..143 : EMA scan + excl cumsum       (b=blk-128)
//  blk 144..159 : rW1[0:512] -> bf16 Bt[kt][col][32]  (kt=blk-144, linear)
// ---------------------------------------------------------------------------
__global__ __launch_bounds__(512) void k_p1(
    const float* __restrict__ log_anchor, const float* __restrict__ unit_mask,
    const float* __restrict__ sealed_mask, const float* __restrict__ silence_mask,
    const float* __restrict__ local_rate_ema,
    const float* __restrict__ spk_embed, const float* __restrict__ spk_W,
    const float* __restrict__ spk_b, const float* __restrict__ rW1,
    float* __restrict__ lr_seq, float* __restrict__ prefix_prev,
    float* __restrict__ spk_ctx, unsigned short* __restrict__ BtG)
{
  __shared__ float shbuf[12672];
  const int tid = threadIdx.x;
  const int blk = blockIdx.x;

  if (blk < 128){
    const int b = blk >> 3, n0 = (blk & 7)*64;
    float* se      = shbuf;
    float* partial = shbuf + 512;
    se[tid] = spk_embed[b*512 + tid];
    __syncthreads();
    const int nq = tid & 15, q = tid >> 4;
    float a0=0.f, a1=0.f, a2=0.f, a3=0.f;
    const float* wp = spk_W + (q*16)*512 + n0 + nq*4;
    #pragma unroll
    for (int kk = 0; kk < 16; ++kk){
      float s = se[q*16 + kk];
      float4 v = *(const float4*)(wp + kk*512);
      a0 = fmaf(s, v.x, a0); a1 = fmaf(s, v.y, a1);
      a2 = fmaf(s, v.z, a2); a3 = fmaf(s, v.w, a3);
    }
    *(float4*)&partial[q*64 + nq*4] = make_float4(a0,a1,a2,a3);
    __syncthreads();
    if (tid < 64){
      float acc = spk_b[n0 + tid];
      #pragma unroll
      for (int qq = 0; qq < 32; ++qq) acc += partial[qq*64 + tid];
      spk_ctx[b*512 + n0 + tid] = tanhf(acc);
    }

  } else if (blk < 144){
    const int b = blk - 128;
    float* s_la = shbuf;
    float* s_um = shbuf + 2112;
    float* s_sm = shbuf + 4224;
    float* s_si = shbuf + 6336;
    float* s_or = shbuf + 8448;
    float* s_op = shbuf + 10560;
    #pragma unroll
    for (int p = 0; p < 4; ++p){
      int t = tid + p*512, g = b*T_ + t, ix = idx32(t);
      s_la[ix] = log_anchor[g];
      s_um[ix] = unit_mask[g];
      s_sm[ix] = sealed_mask[g];
      s_si[ix] = silence_mask[g];
    }
    __syncthreads();
    if (tid < 64){
      const float CE = (float)(1.0 - 0.95);
      const int base = tid*32;
      float A = 1.f, Bv = 0.f, S = 0.f;
      for (int j = 0; j < 32; ++j){
        int ix = idx32(base + j);
        float mask   = clamp01(s_um[ix]);
        float sealed = clamp01(s_sm[ix]);
        float sil    = clamp01(s_si[ix])*mask;
        float speech = mask*sealed*(1.f-sil);
        float cm = CE*speech;
        A  = (1.f-cm)*A;
        Bv = (1.f-cm)*Bv + cm*s_la[ix];
        S += speech;
      }
      float Ai=A, Bi=Bv, Si=S;
      for (int off = 1; off < 64; off <<= 1){
        float Ap=__shfl_up(Ai,off), Bp=__shfl_up(Bi,off), Sp=__shfl_up(Si,off);
        if (tid >= off){ Bi = Ai*Bp + Bi; Ai *= Ap; Si += Sp; }
      }
      float Ae=__shfl_up(Ai,1), Be=__shfl_up(Bi,1), Se=__shfl_up(Si,1);
      if (tid==0){ Ae=1.f; Be=0.f; Se=0.f; }
      float r  = Ae*local_rate_ema[b] + Be;
      float ps = Se;
      for (int j = 0; j < 32; ++j){
        int ix = idx32(base + j);
        float mask   = clamp01(s_um[ix]);
        float sealed = clamp01(s_sm[ix]);
        float sil    = clamp01(s_si[ix])*mask;
        float speech = mask*sealed*(1.f-sil);
        s_or[ix] = r;
        s_op[ix] = ps;
        r  += CE*speech*(s_la[ix]-r);
        ps += speech;
      }
    }
    __syncthreads();
    #pragma unroll
    for (int p = 0; p < 4; ++p){
      int t = tid + p*512, g = b*T_ + t, ix = idx32(t);
      lr_seq[g]      = s_or[ix];
      prefix_prev[g] = s_op[ix];
    }

  } else {
    const int kt = blk - 144;
    unsigned short* sb = (unsigned short*)shbuf;   // [32][512]
    #pragma unroll
    for (int p = 0; p < 32; ++p){
      int id = tid + p*512;
      int kl = id >> 9, col = id & 511;
      sb[kl*512 + col] = bf16_rne(rW1[(kt*32 + kl)*512 + col]);
    }
    __syncthreads();
    const int col = tid;
    unsigned q[16];
    #pragma unroll
    for (int p = 0; p < 16; ++p)
      q[p] = (unsigned)sb[(2*p)*512 + col] | ((unsigned)sb[(2*p+1)*512 + col] << 16);
    uint4* dst = (uint4*)(BtG + kt*16384 + col*32);
    dst[0] = make_uint4(q[0], q[1], q[2], q[3]);
    dst[1] = make_uint4(q[4], q[5], q[6], q[7]);
    dst[2] = make_uint4(q[8], q[9], q[10], q[11]);
    dst[3] = make_uint4(q[12], q[13], q[14], q[15]);
  }
}

// ---------------------------------------------------------------------------
// P2: 256 blocks x 512 threads.
//  blk   0..127 : spk_pb[b, slice] = sc@rW1[512:1024,slice] + rb1
//  blk 128..255 : cpart[b][s] = sum_slice gelu(ac)*cW2   (coarse partials)
// ---------------------------------------------------------------------------
__global__ __launch_bounds__(512) void k_p2(
    const float* __restrict__ spk_ctx, const float* __restrict__ global_rate,
    const float* __restrict__ cW1, const float* __restrict__ cb1,
    const float* __restrict__ cW2, const float* __restrict__ rW1,
    const float* __restrict__ rb1,
    float* __restrict__ spk_pb, float* __restrict__ cpart)
{
  __shared__ float sc[512];
  __shared__ float partial[32*64];
  const int tid = threadIdx.x;
  const int blk = blockIdx.x;
  const bool isAC = blk >= 128;
  const int bb = isAC ? (blk - 128) : blk;
  const int b = bb >> 3, s = bb & 7, n0 = s*64;

  sc[tid] = spk_ctx[b*512 + tid];
  __syncthreads();
  const int nq = tid & 15, q = tid >> 4;
  const float* mat = isAC ? cW1 : (rW1 + 512*512);
  float a0=0.f, a1=0.f, a2=0.f, a3=0.f;
  const float* wp = mat + (q*16)*512 + n0 + nq*4;
  #pragma unroll
  for (int kk = 0; kk < 16; ++kk){
    float sv = sc[q*16 + kk];
    float4 v = *(const float4*)(wp + kk*512);
    a0 = fmaf(sv, v.x, a0); a1 = fmaf(sv, v.y, a1);
    a2 = fmaf(sv, v.z, a2); a3 = fmaf(sv, v.w, a3);
  }
  *(float4*)&partial[q*64 + nq*4] = make_float4(a0,a1,a2,a3);
  __syncthreads();
  if (tid < 64){
    const int n = n0 + tid;
    float acc = 0.f;
    #pragma unroll
    for (int qq = 0; qq < 32; ++qq) acc += partial[qq*64 + tid];
    if (!isAC){
      spk_pb[b*512 + n] = acc + rb1[n];
    } else {
      float ac = acc + cb1[n] + global_rate[b]*cW1[512*512 + n];
      float g  = gelu_exact(ac)*cW2[n];
      g += __shfl_xor(g,1);  g += __shfl_xor(g,2);  g += __shfl_xor(g,4);
      g += __shfl_xor(g,8);  g += __shfl_xor(g,16); g += __shfl_xor(g,32);
      if (tid == 0) cpart[b*8 + s] = g;
    }
  }
}

// ---------------------------------------------------------------------------
// K3: two-tile pipelined block. 256 blocks x 512 thr (8 waves).
// Block = rows [blk*128, +128): T0 = rows 0-63, T1 = rows 64-127.
// Wave w owns cols [w*64,+64); per tile acc[4][4] = 64 AGPR (both live: 128).
// Schedule: A0-wall -> loop0{MFMA acc0 + A1-compute interleaved} ->
//           loop1{MFMA acc1 + T0-epilogue interleaved} -> T1-epilogue wall.
// B read directly from L2 (BtG, 640 KB, chip-shared). Barrier-free kt loops.
// ---------------------------------------------------------------------------
__global__ __launch_bounds__(512, 2) void k_heavy(
    const int*   __restrict__ content_units, const float* __restrict__ log_anchor,
    const float* __restrict__ unit_mask,     const float* __restrict__ sealed_mask,
    const float* __restrict__ sep_hint,      const float* __restrict__ edge_cue,
    const float* __restrict__ global_rate,   const float* __restrict__ silence_mask,
    const float* __restrict__ embed,         const float* __restrict__ feat_W,
    const float* __restrict__ feat_b,        const float* __restrict__ rW1,
    const float* __restrict__ rW2,           const float* __restrict__ rb2,
    const float* __restrict__ cb2,
    const float* __restrict__ lr_seq,        const float* __restrict__ prefix_prev,
    const float* __restrict__ spk_pb,        const float* __restrict__ cpart,
    const unsigned short* __restrict__ BtG,
    float* __restrict__ out)
{
  __shared__ __align__(16) unsigned short As0[64*ASP];   // 66560 B
  __shared__ __align__(16) unsigned short As1[64*ASP];   // 66560 B
  __shared__ float r_la[128], r_lr[128], r_sil[128], r_sep[128], r_edge[128], r_mask[128];
  __shared__ int   r_u[128];
  __shared__ float r_gt[128], r_speech[128], r_silc[128], r_resmul[128], r_tau[128];
  __shared__ float pdred[8][64];

  const int m0   = blockIdx.x*128;
  const int b    = m0 >> 11;
  const int tid  = threadIdx.x;
  const int lane = tid & 63;
  const int w    = tid >> 6;                // 0..7, cols [w*64, +64)
  const int l15  = lane & 15, kg = lane >> 4;

  if (tid < 128){
    int m = m0 + tid;
    float csum = cb2[0];
    #pragma unroll
    for (int s = 0; s < 8; ++s) csum += cpart[b*8 + s];
    float coarse = 0.2f*tanhf(csum);
    float mask   = clamp01(unit_mask[m]);
    float sealed = clamp01(sealed_mask[m]);
    float sil    = clamp01(silence_mask[m])*mask;
    float commit = mask*sealed;
    float silc   = commit*sil;
    float speech = commit*(1.f-sil);
    float la = log_anchor[m];
    float lr = lr_seq[m];
    float gap = clampf(global_rate[b]-lr, -0.35f, 0.35f)*commit;
    float gt  = (gap + coarse*commit)*commit;
    float cold = clamp01(prefix_prev[m]*0.5f);
    float dur  = expf(la);
    float shortv = clamp01(fmaxf(dur,1.f)-1.f);
    r_la[tid]=la; r_lr[tid]=lr; r_sil[tid]=sil;
    r_sep[tid]=sep_hint[m]; r_edge[tid]=edge_cue[m]; r_mask[tid]=mask;
    r_u[tid]=content_units[m];
    r_gt[tid]=gt; r_speech[tid]=speech; r_silc[tid]=silc;
    r_resmul[tid]=cold*shortv*speech;
    r_tau[tid]=0.35f*((dur<2.0f)?0.35f:1.0f);
  }
  __syncthreads();

  // A-compute thread mapping (per tile): 4 rows x 16 k per thread.
  const int rg  = (tid >> 5)*4;             // local row group 0,4..60
  const int ksl = tid & 31;                 // k segment (x16)

  // macro-ish lambda: compute 8 els for 4 rows at chunk c8 of tile (rb = row base 0/64)
  auto a_chunk = [&](unsigned short* dst, int rb, int c8){
    const int jg = ksl*16 + c8*8;
    float4 w0a = *(const float4*)(feat_W + jg),        w0b = *(const float4*)(feat_W + jg + 4);
    float4 w1a = *(const float4*)(feat_W + 512 + jg),  w1b = *(const float4*)(feat_W + 512 + jg + 4);
    float4 w2a = *(const float4*)(feat_W + 1024 + jg), w2b = *(const float4*)(feat_W + 1024 + jg + 4);
    float4 w3a = *(const float4*)(feat_W + 1536 + jg), w3b = *(const float4*)(feat_W + 1536 + jg + 4);
    float4 w4a = *(const float4*)(feat_W + 2048 + jg), w4b = *(const float4*)(feat_W + 2048 + jg + 4);
    float4 ba  = *(const float4*)(feat_b + jg),        bb4 = *(const float4*)(feat_b + jg + 4);
    #pragma unroll
    for (int i = 0; i < 4; ++i){
      const int lrow = rg + i;              // tile-local row
      const int grow = rb + lrow;           // block-local row for r_*
      const int u = r_u[grow];
      const float la=r_la[grow], lr=r_lr[grow], si=r_sil[grow],
                  sp=r_sep[grow], ed=r_edge[grow], mk=r_mask[grow];
      const float* eb = embed + (size_t)u*DIM_ + jg;
      float4 ea = *(const float4*)eb, eb4v = *(const float4*)(eb + 4);
      float f0 = ea.x + ba.x + la*w0a.x + lr*w1a.x + si*w2a.x + sp*w3a.x + ed*w4a.x;
      float f1 = ea.y + ba.y + la*w0a.y + lr*w1a.y + si*w2a.y + sp*w3a.y + ed*w4a.y;
      float f2 = ea.z + ba.z + la*w0a.z + lr*w1a.z + si*w2a.z + sp*w3a.z + ed*w4a.z;
      float f3 = ea.w + ba.w + la*w0a.w + lr*w1a.w + si*w2a.w + sp*w3a.w + ed*w4a.w;
      float f4 = eb4v.x + bb4.x + la*w0b.x + lr*w1b.x + si*w2b.x + sp*w3b.x + ed*w4b.x;
      float f5 = eb4v.y + bb4.y + la*w0b.y + lr*w1b.y + si*w2b.y + sp*w3b.y + ed*w4b.y;
      float f6 = eb4v.z + bb4.z + la*w0b.z + lr*w1b.z + si*w2b.z + sp*w3b.z + ed*w4b.z;
      float f7 = eb4v.w + bb4.w + la*w0b.w + lr*w1b.w + si*w2b.w + sp*w3b.w + ed*w4b.w;
      unsigned p0 = cvt_pk_bf16(fast_tanh(f0)*mk, fast_tanh(f1)*mk);
      unsigned p1 = cvt_pk_bf16(fast_tanh(f2)*mk, fast_tanh(f3)*mk);
      unsigned p2 = cvt_pk_bf16(fast_tanh(f4)*mk, fast_tanh(f5)*mk);
      unsigned p3 = cvt_pk_bf16(fast_tanh(f6)*mk, fast_tanh(f7)*mk);
      *(uint4*)&dst[lrow*ASP + ksl*16 + c8*8] = make_uint4(p0,p1,p2,p3);
    }
  };

  // ---- A0 wall ----
  a_chunk(As0, 0, 0);
  a_chunk(As0, 0, 1);
  asm volatile("s_waitcnt lgkmcnt(0)" ::: "memory");
  __builtin_amdgcn_s_barrier();

  // epilogue column constants (live through both loops)
  const int colb = w*64 + l15;
  float stv[4], wbv[4], w2v[4];
  #pragma unroll
  for (int c=0;c<4;++c){
    int col = colb + c*16;
    stv[c] = spk_pb[b*DIM_ + col];
    wbv[c] = rW1[1024*DIM_ + col];
    w2v[c] = rW2[col];
  }

  const unsigned short* bwave = BtG + (w*64 + l15)*32 + kg*8;

  f32x4 acc0[4][4];
  #pragma unroll
  for (int r=0;r<4;++r)
    #pragma unroll
    for (int c=0;c<4;++c) acc0[r][c] = (f32x4)0.0f;

  // ---- loop0: MFMA T0 + interleaved A1-compute ----
  #pragma unroll
  for (int kt = 0; kt < 16; ++kt){
    const unsigned short* bkt = bwave + kt*16384;
    short8_t af[4], bfr[4];
    #pragma unroll
    for (int r=0;r<4;++r)
      af[r] = *(const short8_t*)&As0[(r*16 + l15)*ASP + kt*32 + kg*8];
    #pragma unroll
    for (int c=0;c<4;++c)
      bfr[c] = *(const short8_t*)(bkt + c*512);
    #pragma unroll
    for (int r=0;r<4;++r)
      #pragma unroll
      for (int c=0;c<4;++c)
        acc0[r][c] = __builtin_amdgcn_mfma_f32_16x16x32_bf16(af[r], bfr[c], acc0[r][c], 0, 0, 0);
    if (kt == 4)  a_chunk(As1, 64, 0);      // A1 half, overlaps MFMA
    if (kt == 10) a_chunk(As1, 64, 1);
  }
  asm volatile("s_waitcnt lgkmcnt(0)" ::: "memory");   // As1 writes landed
  __builtin_amdgcn_s_barrier();

  f32x4 acc1[4][4];
  #pragma unroll
  for (int r=0;r<4;++r)
    #pragma unroll
    for (int c=0;c<4;++c) acc1[r][c] = (f32x4)0.0f;
  float pd0[4][4];

  // ---- loop1: MFMA T1 + interleaved T0 epilogue (one (r,g) unit per kt) ----
  #pragma unroll
  for (int kt = 0; kt < 16; ++kt){
    const unsigned short* bkt = bwave + kt*16384;
    short8_t af[4], bfr[4];
    #pragma unroll
    for (int r=0;r<4;++r)
      af[r] = *(const short8_t*)&As1[(r*16 + l15)*ASP + kt*32 + kg*8];
    #pragma unroll
    for (int c=0;c<4;++c)
      bfr[c] = *(const short8_t*)(bkt + c*512);
    #pragma unroll
    for (int r=0;r<4;++r)
      #pragma unroll
      for (int c=0;c<4;++c)
        acc1[r][c] = __builtin_amdgcn_mfma_f32_16x16x32_bf16(af[r], bfr[c], acc1[r][c], 0, 0, 0);
    {   // T0 epilogue unit (r,g) = (kt>>2, kt&3) — compile-time via full unroll
      const int er = kt >> 2, eg = kt & 3;
      const int row = er*16 + kg*4 + eg;     // C/D: row=(lane>>4)*4+reg
      float gt = r_gt[row];
      float s = 0.f;
      #pragma unroll
      for (int c=0;c<4;++c){
        float x = acc0[er][c][eg] + stv[c] + gt*wbv[c];
        s += gelu_fast(x)*w2v[c];
      }
      pd0[er][eg] = s;
    }
  }

  // ---- T0 reduce + write ----
  #pragma unroll
  for (int er=0;er<4;++er){
    #pragma unroll
    for (int eg=0;eg<4;++eg){
      float s = pd0[er][eg];
      s += __shfl_xor(s,1); s += __shfl_xor(s,2);
      s += __shfl_xor(s,4); s += __shfl_xor(s,8);
      if (l15 == 0) pdred[w][er*16 + kg*4 + eg] = s;
    }
  }
  __syncthreads();
  if (tid < 64){
    float v = rb2[0];
    #pragma unroll
    for (int ww=0;ww<8;++ww) v += pdred[ww][tid];
    float residual = 0.35f*tanhf(v) * r_resmul[tid];
    float gt = r_gt[tid];
    out[m0+tid] = clampf(gt + residual, -1.2f, 1.2f)*r_speech[tid]
                + clampf(gt, -r_tau[tid], r_tau[tid])*r_silc[tid];
  }
  __syncthreads();   // pdred reusable

  // ---- T1 epilogue wall ----
  #pragma unroll
  for (int er=0;er<4;++er){
    #pragma unroll
    for (int eg=0;eg<4;++eg){
      const int row = 64 + er*16 + kg*4 + eg;
      float gt = r_gt[row];
      float s = 0.f;
      #pragma unroll
      for (int c=0;c<4;++c){
        float x = acc1[er][c][eg] + stv[c] + gt*wbv[c];
        s += gelu_fast(x)*w2v[c];
      }
      s += __shfl_xor(s,1); s += __shfl_xor(s,2);
      s += __shfl_xor(s,4); s += __shfl_xor(s,8);
      if (l15 == 0) pdred[w][er*16 + kg*4 + eg] = s;
    }
  }
  __syncthreads();
  if (tid < 64){
    float v = rb2[0];
    #pragma unroll
    for (int ww=0;ww<8;++ww) v += pdred[ww][tid];
    int grow = 64 + tid;
    float residual = 0.35f*tanhf(v) * r_resmul[grow];
    float gt = r_gt[grow];
    out[m0+grow] = clampf(gt + residual, -1.2f, 1.2f)*r_speech[grow]
                 + clampf(gt, -r_tau[grow], r_tau[grow])*r_silc[grow];
  }
}

// ---------------------------------------------------------------------------
extern "C" void kernel_launch(void* const* d_in, const int* in_sizes, int n_in,
                              void* d_out, int out_size, void* d_ws, size_t ws_size,
                              hipStream_t stream)
{
  const int*   content_units  = (const int*)  d_in[0];
  const float* log_anchor     = (const float*)d_in[1];
  const float* unit_mask      = (const float*)d_in[2];
  const float* sealed_mask    = (const float*)d_in[3];
  const float* sep_hint       = (const float*)d_in[4];
  const float* edge_cue       = (const float*)d_in[5];
  const float* global_rate    = (const float*)d_in[6];
  const float* local_rate_ema = (const float*)d_in[7];
  const float* silence_mask   = (const float*)d_in[8];
  const float* spk_embed      = (const float*)d_in[9];
  const float* embed          = (const float*)d_in[10];
  const float* feat_W         = (const float*)d_in[11];
  const float* feat_b         = (const float*)d_in[12];
  const float* spk_W          = (const float*)d_in[13];
  const float* spk_b          = (const float*)d_in[14];
  const float* cW1            = (const float*)d_in[15];
  const float* cb1            = (const float*)d_in[16];
  const float* cW2            = (const float*)d_in[17];
  const float* cb2            = (const float*)d_in[18];
  const float* rW1            = (const float*)d_in[19];
  const float* rb1            = (const float*)d_in[20];
  const float* rW2            = (const float*)d_in[21];
  const float* rb2            = (const float*)d_in[22];
  float* out = (float*)d_out;

  float* ws       = (float*)d_ws;
  float* lr_seq   = ws;                  // 32768
  float* prefix   = ws + 32768;          // 32768
  float* spk_ctx  = ws + 65536;          // 8192
  float* spk_pb   = ws + 73728;          // 8192
  float* cpart    = ws + 81920;          // 128
  unsigned short* BtG = (unsigned short*)(ws + 82048);   // 512 KB bf16

  k_p1<<<160, 512, 0, stream>>>(log_anchor, unit_mask, sealed_mask, silence_mask,
                                local_rate_ema, spk_embed, spk_W, spk_b, rW1,
                                lr_seq, prefix, spk_ctx, BtG);
  k_p2<<<256, 512, 0, stream>>>(spk_ctx, global_rate, cW1, cb1, cW2, rW1, rb1,
                                spk_pb, cpart);
  k_heavy<<<M_/128, 512, 0, stream>>>(content_units, log_anchor, unit_mask, sealed_mask,
                                      sep_hint, edge_cue, global_rate, silence_mask,
                                      embed, feat_W, feat_b, rW1, rW2, rb2, cb2,
                                      lr_seq, prefix, spk_pb, cpart, BtG, out);
}

// Round 12
// 52.334 us; speedup vs baseline: 1.4124x; 1.0033x over previous
//
#include <hip/hip_runtime.h>
#include <math.h>

#define B_    16
#define T_    2048
#define DIM_  512
#define M_    (B_*T_)
#define ASP   520     // A LDS row stride in shorts (1040 B)

typedef __attribute__((ext_vector_type(8))) short short8_t;   // 8 x bf16 bits
typedef __attribute__((ext_vector_type(4))) float f32x4;

__device__ __forceinline__ float clamp01(float x){ return fminf(fmaxf(x,0.f),1.f); }
__device__ __forceinline__ float clampf(float x,float lo,float hi){ return fminf(fmaxf(x,lo),hi); }
__device__ __forceinline__ float gelu_exact(float x){ return 0.5f*x*(1.f+erff(x*0.70710678118654752f)); }
__device__ __forceinline__ unsigned short bf16_rne(float f){
  unsigned u = __float_as_uint(f);
  unsigned r = (u + 0x7fffu + ((u>>16)&1u)) >> 16;
  return (unsigned short)r;
}
__device__ __forceinline__ float fast_tanh(float x){
  float e = __expf(2.0f*x);
  return 1.0f - 2.0f*__builtin_amdgcn_rcpf(e + 1.0f);
}
// tanh-form GELU (max abs dev ~3e-4; epilogue only)
__device__ __forceinline__ float gelu_fast(float x){
  float u = 0.7978845608028654f*fmaf(0.044715f*x, x*x, x);
  return 0.5f*x*(1.f + fast_tanh(u));
}
__device__ __forceinline__ unsigned cvt_pk_bf16(float lo, float hi){
  unsigned r;
  asm("v_cvt_pk_bf16_f32 %0, %1, %2" : "=v"(r) : "v"(lo), "v"(hi));
  return r;
}
__device__ __forceinline__ int idx32(int t){ return t + (t>>5); }  // pad stride 33

// ---------------------------------------------------------------------------
// P1: 160 blocks x 512 threads.
//  blk   0..127 : spk_ctx[b, s*64 .. s*64+64)  (b=blk>>3, s=blk&7)
//  blk 128..143 : EMA scan + excl cumsum       (b=blk-128)
//  blk 144..159 : rW1[0:512] -> bf16 Bt[kt][col][32]  (kt=blk-144, linear)
// ---------------------------------------------------------------------------
__global__ __launch_bounds__(512) void k_p1(
    const float* __restrict__ log_anchor, const float* __restrict__ unit_mask,
    const float* __restrict__ sealed_mask, const float* __restrict__ silence_mask,
    const float* __restrict__ local_rate_ema,
    const float* __restrict__ spk_embed, const float* __restrict__ spk_W,
    const float* __restrict__ spk_b, const float* __restrict__ rW1,
    float* __restrict__ lr_seq, float* __restrict__ prefix_prev,
    float* __restrict__ spk_ctx, unsigned short* __restrict__ BtG)
{
  __shared__ float shbuf[12672];
  const int tid = threadIdx.x;
  const int blk = blockIdx.x;

  if (blk < 128){
    const int b = blk >> 3, n0 = (blk & 7)*64;
    float* se      = shbuf;
    float* partial = shbuf + 512;
    se[tid] = spk_embed[b*512 + tid];
    __syncthreads();
    const int nq = tid & 15, q = tid >> 4;
    float a0=0.f, a1=0.f, a2=0.f, a3=0.f;
    const float* wp = spk_W + (q*16)*512 + n0 + nq*4;
    #pragma unroll
    for (int kk = 0; kk < 16; ++kk){
      float s = se[q*16 + kk];
      float4 v = *(const float4*)(wp + kk*512);
      a0 = fmaf(s, v.x, a0); a1 = fmaf(s, v.y, a1);
      a2 = fmaf(s, v.z, a2); a3 = fmaf(s, v.w, a3);
    }
    *(float4*)&partial[q*64 + nq*4] = make_float4(a0,a1,a2,a3);
    __syncthreads();
    if (tid < 64){
      float acc = spk_b[n0 + tid];
      #pragma unroll
      for (int qq = 0; qq < 32; ++qq) acc += partial[qq*64 + tid];
      spk_ctx[b*512 + n0 + tid] = tanhf(acc);
    }

  } else if (blk < 144){
    const int b = blk - 128;
    float* s_la = shbuf;
    float* s_um = shbuf + 2112;
    float* s_sm = shbuf + 4224;
    float* s_si = shbuf + 6336;
    float* s_or = shbuf + 8448;
    float* s_op = shbuf + 10560;
    #pragma unroll
    for (int p = 0; p < 4; ++p){
      int t = tid + p*512, g = b*T_ + t, ix = idx32(t);
      s_la[ix] = log_anchor[g];
      s_um[ix] = unit_mask[g];
      s_sm[ix] = sealed_mask[g];
      s_si[ix] = silence_mask[g];
    }
    __syncthreads();
    if (tid < 64){
      const float CE = (float)(1.0 - 0.95);
      const int base = tid*32;
      float A = 1.f, Bv = 0.f, S = 0.f;
      for (int j = 0; j < 32; ++j){
        int ix = idx32(base + j);
        float mask   = clamp01(s_um[ix]);
        float sealed = clamp01(s_sm[ix]);
        float sil    = clamp01(s_si[ix])*mask;
        float speech = mask*sealed*(1.f-sil);
        float cm = CE*speech;
        A  = (1.f-cm)*A;
        Bv = (1.f-cm)*Bv + cm*s_la[ix];
        S += speech;
      }
      float Ai=A, Bi=Bv, Si=S;
      for (int off = 1; off < 64; off <<= 1){
        float Ap=__shfl_up(Ai,off), Bp=__shfl_up(Bi,off), Sp=__shfl_up(Si,off);
        if (tid >= off){ Bi = Ai*Bp + Bi; Ai *= Ap; Si += Sp; }
      }
      float Ae=__shfl_up(Ai,1), Be=__shfl_up(Bi,1), Se=__shfl_up(Si,1);
      if (tid==0){ Ae=1.f; Be=0.f; Se=0.f; }
      float r  = Ae*local_rate_ema[b] + Be;
      float ps = Se;
      for (int j = 0; j < 32; ++j){
        int ix = idx32(base + j);
        float mask   = clamp01(s_um[ix]);
        float sealed = clamp01(s_sm[ix]);
        float sil    = clamp01(s_si[ix])*mask;
        float speech = mask*sealed*(1.f-sil);
        s_or[ix] = r;
        s_op[ix] = ps;
        r  += CE*speech*(s_la[ix]-r);
        ps += speech;
      }
    }
    __syncthreads();
    #pragma unroll
    for (int p = 0; p < 4; ++p){
      int t = tid + p*512, g = b*T_ + t, ix = idx32(t);
      lr_seq[g]      = s_or[ix];
      prefix_prev[g] = s_op[ix];
    }

  } else {
    const int kt = blk - 144;
    unsigned short* sb = (unsigned short*)shbuf;   // [32][512]
    #pragma unroll
    for (int p = 0; p < 32; ++p){
      int id = tid + p*512;
      int kl = id >> 9, col = id & 511;
      sb[kl*512 + col] = bf16_rne(rW1[(kt*32 + kl)*512 + col]);
    }
    __syncthreads();
    const int col = tid;
    unsigned q[16];
    #pragma unroll
    for (int p = 0; p < 16; ++p)
      q[p] = (unsigned)sb[(2*p)*512 + col] | ((unsigned)sb[(2*p+1)*512 + col] << 16);
    uint4* dst = (uint4*)(BtG + kt*16384 + col*32);
    dst[0] = make_uint4(q[0], q[1], q[2], q[3]);
    dst[1] = make_uint4(q[4], q[5], q[6], q[7]);
    dst[2] = make_uint4(q[8], q[9], q[10], q[11]);
    dst[3] = make_uint4(q[12], q[13], q[14], q[15]);
  }
}

// ---------------------------------------------------------------------------
// P2: 256 blocks x 512 threads.
//  blk   0..127 : spk_pb[b, slice] = sc@rW1[512:1024,slice] + rb1
//  blk 128..255 : cpart[b][s] = sum_slice gelu(ac)*cW2   (coarse partials)
// ---------------------------------------------------------------------------
__global__ __launch_bounds__(512) void k_p2(
    const float* __restrict__ spk_ctx, const float* __restrict__ global_rate,
    const float* __restrict__ cW1, const float* __restrict__ cb1,
    const float* __restrict__ cW2, const float* __restrict__ rW1,
    const float* __restrict__ rb1,
    float* __restrict__ spk_pb, float* __restrict__ cpart)
{
  __shared__ float sc[512];
  __shared__ float partial[32*64];
  const int tid = threadIdx.x;
  const int blk = blockIdx.x;
  const bool isAC = blk >= 128;
  const int bb = isAC ? (blk - 128) : blk;
  const int b = bb >> 3, s = bb & 7, n0 = s*64;

  sc[tid] = spk_ctx[b*512 + tid];
  __syncthreads();
  const int nq = tid & 15, q = tid >> 4;
  const float* mat = isAC ? cW1 : (rW1 + 512*512);
  float a0=0.f, a1=0.f, a2=0.f, a3=0.f;
  const float* wp = mat + (q*16)*512 + n0 + nq*4;
  #pragma unroll
  for (int kk = 0; kk < 16; ++kk){
    float sv = sc[q*16 + kk];
    float4 v = *(const float4*)(wp + kk*512);
    a0 = fmaf(sv, v.x, a0); a1 = fmaf(sv, v.y, a1);
    a2 = fmaf(sv, v.z, a2); a3 = fmaf(sv, v.w, a3);
  }
  *(float4*)&partial[q*64 + nq*4] = make_float4(a0,a1,a2,a3);
  __syncthreads();
  if (tid < 64){
    const int n = n0 + tid;
    float acc = 0.f;
    #pragma unroll
    for (int qq = 0; qq < 32; ++qq) acc += partial[qq*64 + tid];
    if (!isAC){
      spk_pb[b*512 + n] = acc + rb1[n];
    } else {
      float ac = acc + cb1[n] + global_rate[b]*cW1[512*512 + n];
      float g  = gelu_exact(ac)*cW2[n];
      g += __shfl_xor(g,1);  g += __shfl_xor(g,2);  g += __shfl_xor(g,4);
      g += __shfl_xor(g,8);  g += __shfl_xor(g,16); g += __shfl_xor(g,32);
      if (tid == 0) cpart[b*8 + s] = g;
    }
  }
}

// ---------------------------------------------------------------------------
// K3: two-tile pipelined block. 256 blocks x 512 thr (8 waves).
// Block = rows [blk*128, +128): T0 = rows 0-63, T1 = rows 64-127.
// Wave w owns cols [w*64,+64); per tile acc[4][4] = 64 AGPR (both live: 128).
// Schedule: A0-wall -> loop0{MFMA acc0 + A1-compute interleaved} ->
//           loop1{MFMA acc1 + T0-epilogue interleaved} -> T1-epilogue wall.
// B read directly from L2 (BtG, 640 KB, chip-shared). Barrier-free kt loops.
// ---------------------------------------------------------------------------
__global__ __launch_bounds__(512, 2) void k_heavy(
    const int*   __restrict__ content_units, const float* __restrict__ log_anchor,
    const float* __restrict__ unit_mask,     const float* __restrict__ sealed_mask,
    const float* __restrict__ sep_hint,      const float* __restrict__ edge_cue,
    const float* __restrict__ global_rate,   const float* __restrict__ silence_mask,
    const float* __restrict__ embed,         const float* __restrict__ feat_W,
    const float* __restrict__ feat_b,        const float* __restrict__ rW1,
    const float* __restrict__ rW2,           const float* __restrict__ rb2,
    const float* __restrict__ cb2,
    const float* __restrict__ lr_seq,        const float* __restrict__ prefix_prev,
    const float* __restrict__ spk_pb,        const float* __restrict__ cpart,
    const unsigned short* __restrict__ BtG,
    float* __restrict__ out)
{
  __shared__ __align__(16) unsigned short As0[64*ASP];   // 66560 B
  __shared__ __align__(16) unsigned short As1[64*ASP];   // 66560 B
  __shared__ float r_la[128], r_lr[128], r_sil[128], r_sep[128], r_edge[128], r_mask[128];
  __shared__ int   r_u[128];
  __shared__ float r_gt[128], r_speech[128], r_silc[128], r_resmul[128], r_tau[128];
  __shared__ float pdred[8][64];

  const int m0   = blockIdx.x*128;
  const int b    = m0 >> 11;
  const int tid  = threadIdx.x;
  const int lane = tid & 63;
  const int w    = tid >> 6;                // 0..7, cols [w*64, +64)
  const int l15  = lane & 15, kg = lane >> 4;

  if (tid < 128){
    int m = m0 + tid;
    float csum = cb2[0];
    #pragma unroll
    for (int s = 0; s < 8; ++s) csum += cpart[b*8 + s];
    float coarse = 0.2f*tanhf(csum);
    float mask   = clamp01(unit_mask[m]);
    float sealed = clamp01(sealed_mask[m]);
    float sil    = clamp01(silence_mask[m])*mask;
    float commit = mask*sealed;
    float silc   = commit*sil;
    float speech = commit*(1.f-sil);
    float la = log_anchor[m];
    float lr = lr_seq[m];
    float gap = clampf(global_rate[b]-lr, -0.35f, 0.35f)*commit;
    float gt  = (gap + coarse*commit)*commit;
    float cold = clamp01(prefix_prev[m]*0.5f);
    float dur  = expf(la);
    float shortv = clamp01(fmaxf(dur,1.f)-1.f);
    r_la[tid]=la; r_lr[tid]=lr; r_sil[tid]=sil;
    r_sep[tid]=sep_hint[m]; r_edge[tid]=edge_cue[m]; r_mask[tid]=mask;
    r_u[tid]=content_units[m];
    r_gt[tid]=gt; r_speech[tid]=speech; r_silc[tid]=silc;
    r_resmul[tid]=cold*shortv*speech;
    r_tau[tid]=0.35f*((dur<2.0f)?0.35f:1.0f);
  }
  __syncthreads();

  // A-compute thread mapping (per tile): 4 rows x 16 k per thread.
  const int rg  = (tid >> 5)*4;             // local row group 0,4..60
  const int ksl = tid & 31;                 // k segment (x16)

  // macro-ish lambda: compute 8 els for 4 rows at chunk c8 of tile (rb = row base 0/64)
  auto a_chunk = [&](unsigned short* dst, int rb, int c8){
    const int jg = ksl*16 + c8*8;
    float4 w0a = *(const float4*)(feat_W + jg),        w0b = *(const float4*)(feat_W + jg + 4);
    float4 w1a = *(const float4*)(feat_W + 512 + jg),  w1b = *(const float4*)(feat_W + 512 + jg + 4);
    float4 w2a = *(const float4*)(feat_W + 1024 + jg), w2b = *(const float4*)(feat_W + 1024 + jg + 4);
    float4 w3a = *(const float4*)(feat_W + 1536 + jg), w3b = *(const float4*)(feat_W + 1536 + jg + 4);
    float4 w4a = *(const float4*)(feat_W + 2048 + jg), w4b = *(const float4*)(feat_W + 2048 + jg + 4);
    float4 ba  = *(const float4*)(feat_b + jg),        bb4 = *(const float4*)(feat_b + jg + 4);
    #pragma unroll
    for (int i = 0; i < 4; ++i){
      const int lrow = rg + i;              // tile-local row
      const int grow = rb + lrow;           // block-local row for r_*
      const int u = r_u[grow];
      const float la=r_la[grow], lr=r_lr[grow], si=r_sil[grow],
                  sp=r_sep[grow], ed=r_edge[grow], mk=r_mask[grow];
      const float* eb = embed + (size_t)u*DIM_ + jg;
      float4 ea = *(const float4*)eb, eb4v = *(const float4*)(eb + 4);
      float f0 = ea.x + ba.x + la*w0a.x + lr*w1a.x + si*w2a.x + sp*w3a.x + ed*w4a.x;
      float f1 = ea.y + ba.y + la*w0a.y + lr*w1a.y + si*w2a.y + sp*w3a.y + ed*w4a.y;
      float f2 = ea.z + ba.z + la*w0a.z + lr*w1a.z + si*w2a.z + sp*w3a.z + ed*w4a.z;
      float f3 = ea.w + ba.w + la*w0a.w + lr*w1a.w + si*w2a.w + sp*w3a.w + ed*w4a.w;
      float f4 = eb4v.x + bb4.x + la*w0b.x + lr*w1b.x + si*w2b.x + sp*w3b.x + ed*w4b.x;
      float f5 = eb4v.y + bb4.y + la*w0b.y + lr*w1b.y + si*w2b.y + sp*w3b.y + ed*w4b.y;
      float f6 = eb4v.z + bb4.z + la*w0b.z + lr*w1b.z + si*w2b.z + sp*w3b.z + ed*w4b.z;
      float f7 = eb4v.w + bb4.w + la*w0b.w + lr*w1b.w + si*w2b.w + sp*w3b.w + ed*w4b.w;
      unsigned p0 = cvt_pk_bf16(fast_tanh(f0)*mk, fast_tanh(f1)*mk);
      unsigned p1 = cvt_pk_bf16(fast_tanh(f2)*mk, fast_tanh(f3)*mk);
      unsigned p2 = cvt_pk_bf16(fast_tanh(f4)*mk, fast_tanh(f5)*mk);
      unsigned p3 = cvt_pk_bf16(fast_tanh(f6)*mk, fast_tanh(f7)*mk);
      *(uint4*)&dst[lrow*ASP + ksl*16 + c8*8] = make_uint4(p0,p1,p2,p3);
    }
  };

  // ---- A0 wall ----
  a_chunk(As0, 0, 0);
  a_chunk(As0, 0, 1);
  asm volatile("s_waitcnt lgkmcnt(0)" ::: "memory");
  __builtin_amdgcn_s_barrier();

  // epilogue column constants (live through both loops)
  const int colb = w*64 + l15;
  float stv[4], wbv[4], w2v[4];
  #pragma unroll
  for (int c=0;c<4;++c){
    int col = colb + c*16;
    stv[c] = spk_pb[b*DIM_ + col];
    wbv[c] = rW1[1024*DIM_ + col];
    w2v[c] = rW2[col];
  }

  const unsigned short* bwave = BtG + (w*64 + l15)*32 + kg*8;

  f32x4 acc0[4][4];
  #pragma unroll
  for (int r=0;r<4;++r)
    #pragma unroll
    for (int c=0;c<4;++c) acc0[r][c] = (f32x4)0.0f;

  // ---- loop0: MFMA T0 + interleaved A1-compute ----
  #pragma unroll
  for (int kt = 0; kt < 16; ++kt){
    const unsigned short* bkt = bwave + kt*16384;
    short8_t af[4], bfr[4];
    #pragma unroll
    for (int r=0;r<4;++r)
      af[r] = *(const short8_t*)&As0[(r*16 + l15)*ASP + kt*32 + kg*8];
    #pragma unroll
    for (int c=0;c<4;++c)
      bfr[c] = *(const short8_t*)(bkt + c*512);
    #pragma unroll
    for (int r=0;r<4;++r)
      #pragma unroll
      for (int c=0;c<4;++c)
        acc0[r][c] = __builtin_amdgcn_mfma_f32_16x16x32_bf16(af[r], bfr[c], acc0[r][c], 0, 0, 0);
    if (kt == 4)  a_chunk(As1, 64, 0);      // A1 half, overlaps MFMA
    if (kt == 10) a_chunk(As1, 64, 1);
  }
  asm volatile("s_waitcnt lgkmcnt(0)" ::: "memory");   // As1 writes landed
  __builtin_amdgcn_s_barrier();

  f32x4 acc1[4][4];
  #pragma unroll
  for (int r=0;r<4;++r)
    #pragma unroll
    for (int c=0;c<4;++c) acc1[r][c] = (f32x4)0.0f;
  float pd0[4][4];

  // ---- loop1: MFMA T1 + interleaved T0 epilogue (one (r,g) unit per kt) ----
  #pragma unroll
  for (int kt = 0; kt < 16; ++kt){
    const unsigned short* bkt = bwave + kt*16384;
    short8_t af[4], bfr[4];
    #pragma unroll
    for (int r=0;r<4;++r)
      af[r] = *(const short8_t*)&As1[(r*16 + l15)*ASP + kt*32 + kg*8];
    #pragma unroll
    for (int c=0;c<4;++c)
      bfr[c] = *(const short8_t*)(bkt + c*512);
    #pragma unroll
    for (int r=0;r<4;++r)
      #pragma unroll
      for (int c=0;c<4;++c)
        acc1[r][c] = __builtin_amdgcn_mfma_f32_16x16x32_bf16(af[r], bfr[c], acc1[r][c], 0, 0, 0);
    {   // T0 epilogue unit (r,g) = (kt>>2, kt&3) — compile-time via full unroll
      const int er = kt >> 2, eg = kt & 3;
      const int row = er*16 + kg*4 + eg;     // C/D: row=(lane>>4)*4+reg
      float gt = r_gt[row];
      float s = 0.f;
      #pragma unroll
      for (int c=0;c<4;++c){
        float x = acc0[er][c][eg] + stv[c] + gt*wbv[c];
        s += gelu_fast(x)*w2v[c];
      }
      pd0[er][eg] = s;
    }
  }

  // ---- T0 reduce + write ----
  #pragma unroll
  for (int er=0;er<4;++er){
    #pragma unroll
    for (int eg=0;eg<4;++eg){
      float s = pd0[er][eg];
      s += __shfl_xor(s,1); s += __shfl_xor(s,2);
      s += __shfl_xor(s,4); s += __shfl_xor(s,8);
      if (l15 == 0) pdred[w][er*16 + kg*4 + eg] = s;
    }
  }
  __syncthreads();
  if (tid < 64){
    float v = rb2[0];
    #pragma unroll
    for (int ww=0;ww<8;++ww) v += pdred[ww][tid];
    float residual = 0.35f*tanhf(v) * r_resmul[tid];
    float gt = r_gt[tid];
    out[m0+tid] = clampf(gt + residual, -1.2f, 1.2f)*r_speech[tid]
                + clampf(gt, -r_tau[tid], r_tau[tid])*r_silc[tid];
  }
  __syncthreads();   // pdred reusable

  // ---- T1 epilogue wall ----
  #pragma unroll
  for (int er=0;er<4;++er){
    #pragma unroll
    for (int eg=0;eg<4;++eg){
      const int row = 64 + er*16 + kg*4 + eg;
      float gt = r_gt[row];
      float s = 0.f;
      #pragma unroll
      for (int c=0;c<4;++c){
        float x = acc1[er][c][eg] + stv[c] + gt*wbv[c];
        s += gelu_fast(x)*w2v[c];
      }
      s += __shfl_xor(s,1); s += __shfl_xor(s,2);
      s += __shfl_xor(s,4); s += __shfl_xor(s,8);
      if (l15 == 0) pdred[w][er*16 + kg*4 + eg] = s;
    }
  }
  __syncthreads();
  if (tid < 64){
    float v = rb2[0];
    #pragma unroll
    for (int ww=0;ww<8;++ww) v += pdred[ww][tid];
    int grow = 64 + tid;
    float residual = 0.35f*tanhf(v) * r_resmul[grow];
    float gt = r_gt[grow];
    out[m0+grow] = clampf(gt + residual, -1.2f, 1.2f)*r_speech[grow]
                 + clampf(gt, -r_tau[grow], r_tau[grow])*r_silc[grow];
  }
}

// ---------------------------------------------------------------------------
extern "C" void kernel_launch(void* const* d_in, const int* in_sizes, int n_in,
                              void* d_out, int out_size, void* d_ws, size_t ws_size,
                              hipStream_t stream)
{
  const int*   content_units  = (const int*)  d_in[0];
  const float* log_anchor     = (const float*)d_in[1];
  const float* unit_mask      = (const float*)d_in[2];
  const float* sealed_mask    = (const float*)d_in[3];
  const float* sep_hint       = (const float*)d_in[4];
  const float* edge_cue       = (const float*)d_in[5];
  const float* global_rate    = (const float*)d_in[6];
  const float* local_rate_ema = (const float*)d_in[7];
  const float* silence_mask   = (const float*)d_in[8];
  const float* spk_embed      = (const float*)d_in[9];
  const float* embed          = (const float*)d_in[10];
  const float* feat_W         = (const float*)d_in[11];
  const float* feat_b         = (const float*)d_in[12];
  const float* spk_W          = (const float*)d_in[13];
  const float* spk_b          = (const float*)d_in[14];
  const float* cW1            = (const float*)d_in[15];
  const float* cb1            = (const float*)d_in[16];
  const float* cW2            = (const float*)d_in[17];
  const float* cb2            = (const float*)d_in[18];
  const float* rW1            = (const float*)d_in[19];
  const float* rb1            = (const float*)d_in[20];
  const float* rW2            = (const float*)d_in[21];
  const float* rb2            = (const float*)d_in[22];
  float* out = (float*)d_out;

  float* ws       = (float*)d_ws;
  float* lr_seq   = ws;                  // 32768
  float* prefix   = ws + 32768;          // 32768
  float* spk_ctx  = ws + 65536;          // 8192
  float* spk_pb   = ws + 73728;          // 8192
  float* cpart    = ws + 81920;          // 128
  unsigned short* BtG = (unsigned short*)(ws + 82048);   // 512 KB bf16

  k_p1<<<160, 512, 0, stream>>>(log_anchor, unit_mask, sealed_mask, silence_mask,
                                local_rate_ema, spk_embed, spk_W, spk_b, rW1,
                                lr_seq, prefix, spk_ctx, BtG);
  k_p2<<<256, 512, 0, stream>>>(spk_ctx, global_rate, cW1, cb1, cW2, rW1, rb1,
                                spk_pb, cpart);
  k_heavy<<<M_/128, 512, 0, stream>>>(content_units, log_anchor, unit_mask, sealed_mask,
                                      sep_hint, edge_cue, global_rate, silence_mask,
                                      embed, feat_W, feat_b, rW1, rW2, rb2, cb2,
                                      lr_seq, prefix, spk_pb, cpart, BtG, out);
}

// Round 13
// 52.131 us; speedup vs baseline: 1.4179x; 1.0039x over previous
//
#include <hip/hip_runtime.h>
#include <math.h>

#define B_    16
#define T_    2048
#define DIM_  512
#define M_    (B_*T_)
#define AP    264   // As row stride in shorts (528 B = 33*16: 16B-aligned, conflict-benign)

typedef __attribute__((ext_vector_type(8))) short short8_t;   // 8 x bf16 bits
typedef __attribute__((ext_vector_type(4))) float f32x4;

__device__ __forceinline__ float clamp01(float x){ return fminf(fmaxf(x,0.f),1.f); }
__device__ __forceinline__ float clampf(float x,float lo,float hi){ return fminf(fmaxf(x,lo),hi); }
__device__ __forceinline__ float gelu_exact(float x){ return 0.5f*x*(1.f+erff(x*0.70710678118654752f)); }
__device__ __forceinline__ unsigned short bf16_rne(float f){
  unsigned u = __float_as_uint(f);
  unsigned r = (u + 0x7fffu + ((u>>16)&1u)) >> 16;
  return (unsigned short)r;
}
__device__ __forceinline__ float fast_tanh(float x){
  float e = __expf(2.0f*x);
  return 1.0f - 2.0f*__builtin_amdgcn_rcpf(e + 1.0f);
}
// tanh-form GELU (max abs dev ~3e-4; epilogue only)
__device__ __forceinline__ float gelu_fast(float x){
  float u = 0.7978845608028654f*fmaf(0.044715f*x, x*x, x);
  return 0.5f*x*(1.f + fast_tanh(u));
}
__device__ __forceinline__ unsigned cvt_pk_bf16(float lo, float hi){
  unsigned r;
  asm("v_cvt_pk_bf16_f32 %0, %1, %2" : "=v"(r) : "v"(lo), "v"(hi));
  return r;
}
__device__ __forceinline__ int idx32(int t){ return t + (t>>5); }  // pad stride 33

// ---------------------------------------------------------------------------
// P1: 160 blocks x 512 threads.
//  blk   0..127 : spk_ctx[b, s*64 .. s*64+64)  (b=blk>>3, s=blk&7)
//  blk 128..143 : EMA scan + excl cumsum       (b=blk-128)
//  blk 144..159 : rW1[0:512] -> bf16 Bt[kt][col][32]  (kt=blk-144, dense)
// ---------------------------------------------------------------------------
__global__ __launch_bounds__(512) void k_p1(
    const float* __restrict__ log_anchor, const float* __restrict__ unit_mask,
    const float* __restrict__ sealed_mask, const float* __restrict__ silence_mask,
    const float* __restrict__ local_rate_ema,
    const float* __restrict__ spk_embed, const float* __restrict__ spk_W,
    const float* __restrict__ spk_b, const float* __restrict__ rW1,
    float* __restrict__ lr_seq, float* __restrict__ prefix_prev,
    float* __restrict__ spk_ctx, unsigned short* __restrict__ BtG)
{
  __shared__ float shbuf[12672];
  const int tid = threadIdx.x;
  const int blk = blockIdx.x;

  if (blk < 128){
    const int b = blk >> 3, n0 = (blk & 7)*64;
    float* se      = shbuf;
    float* partial = shbuf + 512;
    se[tid] = spk_embed[b*512 + tid];
    __syncthreads();
    const int nq = tid & 15, q = tid >> 4;
    float a0=0.f, a1=0.f, a2=0.f, a3=0.f;
    const float* wp = spk_W + (q*16)*512 + n0 + nq*4;
    #pragma unroll
    for (int kk = 0; kk < 16; ++kk){
      float s = se[q*16 + kk];
      float4 v = *(const float4*)(wp + kk*512);
      a0 = fmaf(s, v.x, a0); a1 = fmaf(s, v.y, a1);
      a2 = fmaf(s, v.z, a2); a3 = fmaf(s, v.w, a3);
    }
    *(float4*)&partial[q*64 + nq*4] = make_float4(a0,a1,a2,a3);
    __syncthreads();
    if (tid < 64){
      float acc = spk_b[n0 + tid];
      #pragma unroll
      for (int qq = 0; qq < 32; ++qq) acc += partial[qq*64 + tid];
      spk_ctx[b*512 + n0 + tid] = tanhf(acc);
    }

  } else if (blk < 144){
    const int b = blk - 128;
    float* s_la = shbuf;
    float* s_um = shbuf + 2112;
    float* s_sm = shbuf + 4224;
    float* s_si = shbuf + 6336;
    float* s_or = shbuf + 8448;
    float* s_op = shbuf + 10560;
    #pragma unroll
    for (int p = 0; p < 4; ++p){
      int t = tid + p*512, g = b*T_ + t, ix = idx32(t);
      s_la[ix] = log_anchor[g];
      s_um[ix] = unit_mask[g];
      s_sm[ix] = sealed_mask[g];
      s_si[ix] = silence_mask[g];
    }
    __syncthreads();
    if (tid < 64){
      const float CE = (float)(1.0 - 0.95);
      const int base = tid*32;
      float A = 1.f, Bv = 0.f, S = 0.f;
      for (int j = 0; j < 32; ++j){
        int ix = idx32(base + j);
        float mask   = clamp01(s_um[ix]);
        float sealed = clamp01(s_sm[ix]);
        float sil    = clamp01(s_si[ix])*mask;
        float speech = mask*sealed*(1.f-sil);
        float cm = CE*speech;
        A  = (1.f-cm)*A;
        Bv = (1.f-cm)*Bv + cm*s_la[ix];
        S += speech;
      }
      float Ai=A, Bi=Bv, Si=S;
      for (int off = 1; off < 64; off <<= 1){
        float Ap=__shfl_up(Ai,off), Bp=__shfl_up(Bi,off), Sp=__shfl_up(Si,off);
        if (tid >= off){ Bi = Ai*Bp + Bi; Ai *= Ap; Si += Sp; }
      }
      float Ae=__shfl_up(Ai,1), Be=__shfl_up(Bi,1), Se=__shfl_up(Si,1);
      if (tid==0){ Ae=1.f; Be=0.f; Se=0.f; }
      float r  = Ae*local_rate_ema[b] + Be;
      float ps = Se;
      for (int j = 0; j < 32; ++j){
        int ix = idx32(base + j);
        float mask   = clamp01(s_um[ix]);
        float sealed = clamp01(s_sm[ix]);
        float sil    = clamp01(s_si[ix])*mask;
        float speech = mask*sealed*(1.f-sil);
        s_or[ix] = r;
        s_op[ix] = ps;
        r  += CE*speech*(s_la[ix]-r);
        ps += speech;
      }
    }
    __syncthreads();
    #pragma unroll
    for (int p = 0; p < 4; ++p){
      int t = tid + p*512, g = b*T_ + t, ix = idx32(t);
      lr_seq[g]      = s_or[ix];
      prefix_prev[g] = s_op[ix];
    }

  } else {
    const int kt = blk - 144;
    unsigned short* sb = (unsigned short*)shbuf;   // [32][512]
    #pragma unroll
    for (int p = 0; p < 32; ++p){
      int id = tid + p*512;
      int kl = id >> 9, col = id & 511;
      sb[kl*512 + col] = bf16_rne(rW1[(kt*32 + kl)*512 + col]);
    }
    __syncthreads();
    const int col = tid;
    unsigned q[16];
    #pragma unroll
    for (int p = 0; p < 16; ++p)
      q[p] = (unsigned)sb[(2*p)*512 + col] | ((unsigned)sb[(2*p+1)*512 + col] << 16);
    uint4* dst = (uint4*)(BtG + kt*16384 + col*32);
    dst[0] = make_uint4(q[0], q[1], q[2], q[3]);
    dst[1] = make_uint4(q[4], q[5], q[6], q[7]);
    dst[2] = make_uint4(q[8], q[9], q[10], q[11]);
    dst[3] = make_uint4(q[12], q[13], q[14], q[15]);
  }
}

// ---------------------------------------------------------------------------
// P2: 256 blocks x 512 threads.
//  blk   0..127 : spk_pb[b, slice] = sc@rW1[512:1024,slice] + rb1
//  blk 128..255 : cpart[b][s] = sum_slice gelu(ac)*cW2   (coarse partials)
// ---------------------------------------------------------------------------
__global__ __launch_bounds__(512) void k_p2(
    const float* __restrict__ spk_ctx, const float* __restrict__ global_rate,
    const float* __restrict__ cW1, const float* __restrict__ cb1,
    const float* __restrict__ cW2, const float* __restrict__ rW1,
    const float* __restrict__ rb1,
    float* __restrict__ spk_pb, float* __restrict__ cpart)
{
  __shared__ float sc[512];
  __shared__ float partial[32*64];
  const int tid = threadIdx.x;
  const int blk = blockIdx.x;
  const bool isAC = blk >= 128;
  const int bb = isAC ? (blk - 128) : blk;
  const int b = bb >> 3, s = bb & 7, n0 = s*64;

  sc[tid] = spk_ctx[b*512 + tid];
  __syncthreads();
  const int nq = tid & 15, q = tid >> 4;
  const float* mat = isAC ? cW1 : (rW1 + 512*512);
  float a0=0.f, a1=0.f, a2=0.f, a3=0.f;
  const float* wp = mat + (q*16)*512 + n0 + nq*4;
  #pragma unroll
  for (int kk = 0; kk < 16; ++kk){
    float sv = sc[q*16 + kk];
    float4 v = *(const float4*)(wp + kk*512);
    a0 = fmaf(sv, v.x, a0); a1 = fmaf(sv, v.y, a1);
    a2 = fmaf(sv, v.z, a2); a3 = fmaf(sv, v.w, a3);
  }
  *(float4*)&partial[q*64 + nq*4] = make_float4(a0,a1,a2,a3);
  __syncthreads();
  if (tid < 64){
    const int n = n0 + tid;
    float acc = 0.f;
    #pragma unroll
    for (int qq = 0; qq < 32; ++qq) acc += partial[qq*64 + tid];
    if (!isAC){
      spk_pb[b*512 + n] = acc + rb1[n];
    } else {
      float ac = acc + cb1[n] + global_rate[b]*cW1[512*512 + n];
      float g  = gelu_exact(ac)*cW2[n];
      g += __shfl_xor(g,1);  g += __shfl_xor(g,2);  g += __shfl_xor(g,4);
      g += __shfl_xor(g,8);  g += __shfl_xor(g,16); g += __shfl_xor(g,32);
      if (tid == 0) cpart[b*8 + s] = g;
    }
  }
}

// ---------------------------------------------------------------------------
// K3: occupancy + prefetch. 512 blocks x 512 thr (8 waves), 64 rows x 512 cols.
// Wave w = 64 rows x 64 cols -> acc[4][4] = 64 AGPR.
// __launch_bounds__(512,4): 128-reg cap; lean streaming A-compute (r7-proven
// ~40 VGPR) + explicit double-buffered B register prefetch (16 VGPR).
// 2 blocks/CU (LDS 38.9KB ea) -> 4 waves/SIMD, phase-offset blocks.
// ---------------------------------------------------------------------------
__global__ __launch_bounds__(512, 4) void k_heavy(
    const int*   __restrict__ content_units, const float* __restrict__ log_anchor,
    const float* __restrict__ unit_mask,     const float* __restrict__ sealed_mask,
    const float* __restrict__ sep_hint,      const float* __restrict__ edge_cue,
    const float* __restrict__ global_rate,   const float* __restrict__ silence_mask,
    const float* __restrict__ embed,         const float* __restrict__ feat_W,
    const float* __restrict__ feat_b,        const float* __restrict__ rW1,
    const float* __restrict__ rW2,           const float* __restrict__ rb2,
    const float* __restrict__ cb2,
    const float* __restrict__ lr_seq,        const float* __restrict__ prefix_prev,
    const float* __restrict__ spk_pb,        const float* __restrict__ cpart,
    const unsigned short* __restrict__ BtG,
    float* __restrict__ out)
{
  __shared__ __align__(16) unsigned short As_s[64*AP];   // 33792 B
  __shared__ float r_la[64], r_lr[64], r_sil[64], r_sep[64], r_edge[64], r_mask[64];
  __shared__ int   r_u[64];
  __shared__ float r_gt[64], r_speech[64], r_silc[64], r_resmul[64], r_tau[64];
  __shared__ float pdred[8][64];

  const int m0   = blockIdx.x*64;
  const int b    = m0 >> 11;
  const int tid  = threadIdx.x;
  const int lane = tid & 63;
  const int w    = tid >> 6;                // 0..7, cols [w*64, +64)
  const int l15  = lane & 15, kg = lane >> 4;

  if (tid < 64){
    int m = m0 + tid;
    float csum = cb2[0];
    #pragma unroll
    for (int s = 0; s < 8; ++s) csum += cpart[b*8 + s];
    float coarse = 0.2f*tanhf(csum);
    float mask   = clamp01(unit_mask[m]);
    float sealed = clamp01(sealed_mask[m]);
    float sil    = clamp01(silence_mask[m])*mask;
    float commit = mask*sealed;
    float silc   = commit*sil;
    float speech = commit*(1.f-sil);
    float la = log_anchor[m];
    float lr = lr_seq[m];
    float gap = clampf(global_rate[b]-lr, -0.35f, 0.35f)*commit;
    float gt  = (gap + coarse*commit)*commit;
    float cold = clamp01(prefix_prev[m]*0.5f);
    float dur  = expf(la);
    float shortv = clamp01(fmaxf(dur,1.f)-1.f);
    r_la[tid]=la; r_lr[tid]=lr; r_sil[tid]=sil;
    r_sep[tid]=sep_hint[m]; r_edge[tid]=edge_cue[m]; r_mask[tid]=mask;
    r_u[tid]=content_units[m];
    r_gt[tid]=gt; r_speech[tid]=speech; r_silc[tid]=silc;
    r_resmul[tid]=cold*shortv*speech;
    r_tau[tid]=0.35f*((dur<2.0f)?0.35f:1.0f);
  }
  __syncthreads();

  // lean A-wall: thread = 4 rows x 8 els, processed in 4-el pieces (small live set)
  const int rg  = (tid >> 5)*4;
  const int acv = tid & 31;
  auto a_wall = [&](int h){
    #pragma unroll
    for (int piece = 0; piece < 2; ++piece){
      const int jg = h*256 + acv*8 + piece*4;
      const float4 w0 = *(const float4*)(feat_W + jg);
      const float4 w1 = *(const float4*)(feat_W + 512 + jg);
      const float4 w2 = *(const float4*)(feat_W + 1024 + jg);
      const float4 w3 = *(const float4*)(feat_W + 1536 + jg);
      const float4 w4 = *(const float4*)(feat_W + 2048 + jg);
      const float4 bb = *(const float4*)(feat_b + jg);
      #pragma unroll
      for (int i = 0; i < 4; ++i){
        const int row = rg + i;
        const int u = r_u[row];
        const float la=r_la[row], lr=r_lr[row], si=r_sil[row],
                    sp=r_sep[row], ed=r_edge[row], mk=r_mask[row];
        const float4 e = *(const float4*)(embed + (size_t)u*DIM_ + jg);
        float f0 = e.x + bb.x + la*w0.x + lr*w1.x + si*w2.x + sp*w3.x + ed*w4.x;
        float f1 = e.y + bb.y + la*w0.y + lr*w1.y + si*w2.y + sp*w3.y + ed*w4.y;
        float f2 = e.z + bb.z + la*w0.z + lr*w1.z + si*w2.z + sp*w3.z + ed*w4.z;
        float f3 = e.w + bb.w + la*w0.w + lr*w1.w + si*w2.w + sp*w3.w + ed*w4.w;
        unsigned p0 = cvt_pk_bf16(fast_tanh(f0)*mk, fast_tanh(f1)*mk);
        unsigned p1 = cvt_pk_bf16(fast_tanh(f2)*mk, fast_tanh(f3)*mk);
        *(uint2*)&As_s[row*AP + acv*8 + piece*4] = make_uint2(p0, p1);
      }
    }
  };

  f32x4 acc[4][4];
  #pragma unroll
  for (int r=0;r<4;++r)
    #pragma unroll
    for (int c=0;c<4;++c) acc[r][c] = (f32x4)0.0f;

  const unsigned short* bwave = BtG + (w*64 + l15)*32 + kg*8;
  short8_t bcur[4], bnxt[4];

  // ---- A half 0 + B(0) prefetch ----
  a_wall(0);
  #pragma unroll
  for (int c=0;c<4;++c) bcur[c] = *(const short8_t*)(bwave + c*512);
  asm volatile("s_waitcnt lgkmcnt(0)" ::: "memory");
  __builtin_amdgcn_s_barrier();

  // ---- kt 0..7 : register-double-buffered B, barrier-free ----
  #pragma unroll
  for (int kt = 0; kt < 8; ++kt){
    #pragma unroll
    for (int c=0;c<4;++c)
      bnxt[c] = *(const short8_t*)(bwave + (kt+1)*16384 + c*512);   // kt=7 -> B(8)
    short8_t af[4];
    #pragma unroll
    for (int r=0;r<4;++r)
      af[r] = *(const short8_t*)&As_s[(r*16 + l15)*AP + kt*32 + kg*8];
    #pragma unroll
    for (int r=0;r<4;++r)
      #pragma unroll
      for (int c=0;c<4;++c)
        acc[r][c] = __builtin_amdgcn_mfma_f32_16x16x32_bf16(af[r], bcur[c], acc[r][c], 0, 0, 0);
    #pragma unroll
    for (int c=0;c<4;++c) bcur[c] = bnxt[c];
  }

  // ---- A half 1 (B(8) already in regs; its loads hid under this wall) ----
  __builtin_amdgcn_s_barrier();   // all waves done reading As half 0
  a_wall(1);
  asm volatile("s_waitcnt lgkmcnt(0)" ::: "memory");
  __builtin_amdgcn_s_barrier();

  // ---- kt 8..15 ----
  #pragma unroll
  for (int kt = 8; kt < 16; ++kt){
    if (kt < 15){
      #pragma unroll
      for (int c=0;c<4;++c)
        bnxt[c] = *(const short8_t*)(bwave + (kt+1)*16384 + c*512);
    }
    short8_t af[4];
    #pragma unroll
    for (int r=0;r<4;++r)
      af[r] = *(const short8_t*)&As_s[(r*16 + l15)*AP + (kt-8)*32 + kg*8];
    #pragma unroll
    for (int r=0;r<4;++r)
      #pragma unroll
      for (int c=0;c<4;++c)
        acc[r][c] = __builtin_amdgcn_mfma_f32_16x16x32_bf16(af[r], bcur[c], acc[r][c], 0, 0, 0);
    if (kt < 15){
      #pragma unroll
      for (int c=0;c<4;++c) bcur[c] = bnxt[c];
    }
  }

  // --- epilogue: x = acc + spk_pb[col] + gt[row]*wb[col]; gelu; dot rW2 ---
  const int colb = w*64 + l15;
  float stv[4], wbv[4], w2v[4];
  #pragma unroll
  for (int c=0;c<4;++c){
    int col = colb + c*16;
    stv[c] = spk_pb[b*DIM_ + col];
    wbv[c] = rW1[1024*DIM_ + col];
    w2v[c] = rW2[col];
  }
  #pragma unroll
  for (int r=0;r<4;++r){
    #pragma unroll
    for (int g=0; g<4; ++g){
      int row = r*16 + kg*4 + g;           // C/D: row=(lane>>4)*4+reg
      float gt = r_gt[row];
      float s = 0.f;
      #pragma unroll
      for (int c=0;c<4;++c){
        float x = acc[r][c][g] + stv[c] + gt*wbv[c];
        s += gelu_fast(x)*w2v[c];
      }
      s += __shfl_xor(s,1); s += __shfl_xor(s,2);
      s += __shfl_xor(s,4); s += __shfl_xor(s,8);
      if (l15 == 0) pdred[w][row] = s;
    }
  }
  __syncthreads();
  if (tid < 64){
    float v = rb2[0];
    #pragma unroll
    for (int ww = 0; ww < 8; ++ww) v += pdred[ww][tid];
    float residual = 0.35f*tanhf(v) * r_resmul[tid];
    float gt = r_gt[tid];
    out[m0+tid] = clampf(gt + residual, -1.2f, 1.2f)*r_speech[tid]
                + clampf(gt, -r_tau[tid], r_tau[tid])*r_silc[tid];
  }
}

// ---------------------------------------------------------------------------
extern "C" void kernel_launch(void* const* d_in, const int* in_sizes, int n_in,
                              void* d_out, int out_size, void* d_ws, size_t ws_size,
                              hipStream_t stream)
{
  const int*   content_units  = (const int*)  d_in[0];
  const float* log_anchor     = (const float*)d_in[1];
  const float* unit_mask      = (const float*)d_in[2];
  const float* sealed_mask    = (const float*)d_in[3];
  const float* sep_hint       = (const float*)d_in[4];
  const float* edge_cue       = (const float*)d_in[5];
  const float* global_rate    = (const float*)d_in[6];
  const float* local_rate_ema = (const float*)d_in[7];
  const float* silence_mask   = (const float*)d_in[8];
  const float* spk_embed      = (const float*)d_in[9];
  const float* embed          = (const float*)d_in[10];
  const float* feat_W         = (const float*)d_in[11];
  const float* feat_b         = (const float*)d_in[12];
  const float* spk_W          = (const float*)d_in[13];
  const float* spk_b          = (const float*)d_in[14];
  const float* cW1            = (const float*)d_in[15];
  const float* cb1            = (const float*)d_in[16];
  const float* cW2            = (const float*)d_in[17];
  const float* cb2            = (const float*)d_in[18];
  const float* rW1            = (const float*)d_in[19];
  const float* rb1            = (const float*)d_in[20];
  const float* rW2            = (const float*)d_in[21];
  const float* rb2            = (const float*)d_in[22];
  float* out = (float*)d_out;

  float* ws       = (float*)d_ws;
  float* lr_seq   = ws;                  // 32768
  float* prefix   = ws + 32768;          // 32768
  float* spk_ctx  = ws + 65536;          // 8192
  float* spk_pb   = ws + 73728;          // 8192
  float* cpart    = ws + 81920;          // 128
  unsigned short* BtG = (unsigned short*)(ws + 82048);   // 512 KB bf16

  k_p1<<<160, 512, 0, stream>>>(log_anchor, unit_mask, sealed_mask, silence_mask,
                                local_rate_ema, spk_embed, spk_W, spk_b, rW1,
                                lr_seq, prefix, spk_ctx, BtG);
  k_p2<<<256, 512, 0, stream>>>(spk_ctx, global_rate, cW1, cb1, cW2, rW1, rb1,
                                spk_pb, cpart);
  k_heavy<<<M_/64, 512, 0, stream>>>(content_units, log_anchor, unit_mask, sealed_mask,
                                     sep_hint, edge_cue, global_rate, silence_mask,
                                     embed, feat_W, feat_b, rW1, rW2, rb2, cb2,
                                     lr_seq, prefix, spk_pb, cpart, BtG, out);
}